// Round 1
// baseline (1917.829 us; speedup 1.0000x reference)
//
#include <hip/hip_runtime.h>
#include <hip/hip_bf16.h>
#include <math.h>

#define LSEQ 1024
#define DMODEL 768
#define DINNER 1536
#define DSTATE 16
#define DRANK 48
#define KCONV 4
#define NLAYER 2
#define DBC 80  // DRANK + 2*DSTATE

// ---------------- rmsnorm ----------------
__global__ __launch_bounds__(256) void rmsnorm_k(const float* __restrict__ x,
                                                 const float* __restrict__ w,
                                                 float* __restrict__ xn) {
  int row = blockIdx.x;
  int tid = threadIdx.x;
  const float* xr = x + (size_t)row * DMODEL;
  float ss = 0.f;
  for (int j = tid; j < DMODEL; j += 256) { float v = xr[j]; ss += v * v; }
  __shared__ float red[256];
  red[tid] = ss; __syncthreads();
  for (int s = 128; s > 0; s >>= 1) { if (tid < s) red[tid] += red[tid + s]; __syncthreads(); }
  float scale = rsqrtf(red[0] / (float)DMODEL + 1e-5f);
  float* outr = xn + (size_t)row * DMODEL;
  for (int j = tid; j < DMODEL; j += 256) outr[j] = xr[j] * scale * w[j];
}

// ---------------- generic tiled GEMM ----------------
// C[m,n] = sum_k A[m,k] * B(n,k)
// BLAYOUT 0: B row-major [N,K] (ldb = K stride)    -> B(n,k) = B[n*ldb + k]
// BLAYOUT 1: B row-major [K,N] (ldb = N stride)    -> B(n,k) = B[k*ldb + n]
// EPI bit0: += bias[n]; bit1: softplus; bit2: += resid[m,n]
#define BM 64
#define BN 64
#define BK 16

template<int BLAYOUT, int EPI>
__global__ __launch_bounds__(256) void gemm_k(
    const float* __restrict__ A, int lda,
    const float* __restrict__ B, int ldb,
    float* __restrict__ C, int ldc,
    int M, int N, int K,
    const float* __restrict__ bias,
    const float* __restrict__ resid, int ldr)
{
  __shared__ float As[BK][BM];
  __shared__ float Bs[BK][BN + 4];
  const int tid = threadIdx.x;
  const int bm = blockIdx.y * BM;
  const int bn = blockIdx.x * BN;
  const int ar = tid >> 2;           // 0..63
  const int ak = (tid & 3) << 2;     // 0,4,8,12
  const int bkr = tid >> 4;          // 0..15 (NN layout)
  const int bnc = (tid & 15) << 2;   // 0..60 (NN layout)
  const int ty = tid >> 4, tx = tid & 15;
  float acc[4][4] = {};

  for (int k0 = 0; k0 < K; k0 += BK) {
    float4 av = *(const float4*)(A + (size_t)(bm + ar) * lda + k0 + ak);
    float4 bv = make_float4(0.f, 0.f, 0.f, 0.f);
    if (BLAYOUT == 0) {
      if (bn + ar < N) bv = *(const float4*)(B + (size_t)(bn + ar) * ldb + k0 + ak);
    } else {
      if (bn + bnc + 3 < N) {
        bv = *(const float4*)(B + (size_t)(k0 + bkr) * ldb + bn + bnc);
      } else {
        float t0 = (bn + bnc + 0 < N) ? B[(size_t)(k0 + bkr) * ldb + bn + bnc + 0] : 0.f;
        float t1 = (bn + bnc + 1 < N) ? B[(size_t)(k0 + bkr) * ldb + bn + bnc + 1] : 0.f;
        float t2 = (bn + bnc + 2 < N) ? B[(size_t)(k0 + bkr) * ldb + bn + bnc + 2] : 0.f;
        float t3 = (bn + bnc + 3 < N) ? B[(size_t)(k0 + bkr) * ldb + bn + bnc + 3] : 0.f;
        bv = make_float4(t0, t1, t2, t3);
      }
    }
    __syncthreads();   // previous tile fully consumed
    As[ak + 0][ar] = av.x; As[ak + 1][ar] = av.y;
    As[ak + 2][ar] = av.z; As[ak + 3][ar] = av.w;
    if (BLAYOUT == 0) {
      Bs[ak + 0][ar] = bv.x; Bs[ak + 1][ar] = bv.y;
      Bs[ak + 2][ar] = bv.z; Bs[ak + 3][ar] = bv.w;
    } else {
      *(float4*)&Bs[bkr][bnc] = bv;
    }
    __syncthreads();
#pragma unroll
    for (int kk = 0; kk < BK; kk++) {
      float4 a4 = *(const float4*)&As[kk][ty * 4];
      float4 b4 = *(const float4*)&Bs[kk][tx * 4];
      float a[4] = {a4.x, a4.y, a4.z, a4.w};
      float b[4] = {b4.x, b4.y, b4.z, b4.w};
#pragma unroll
      for (int i = 0; i < 4; i++)
#pragma unroll
        for (int j = 0; j < 4; j++)
          acc[i][j] += a[i] * b[j];
    }
  }

#pragma unroll
  for (int i = 0; i < 4; i++) {
    int row = bm + ty * 4 + i;
#pragma unroll
    for (int j = 0; j < 4; j++) {
      int col = bn + tx * 4 + j;
      if (col < N) {
        float v = acc[i][j];
        if (EPI & 1) v += bias[col];
        if (EPI & 2) v = (v > 20.f) ? v : log1pf(__expf(v));
        if (EPI & 4) v += resid[(size_t)row * ldr + col];
        C[(size_t)row * ldc + col] = v;
      }
    }
  }
}

// ---------------- causal depthwise conv + silu (both directions) ----------------
__global__ __launch_bounds__(256) void conv_silu_k(
    const float* __restrict__ xz,      // [L, 2*DINNER], first DINNER cols = xin
    const float* __restrict__ wf, const float* __restrict__ bf,
    const float* __restrict__ wb, const float* __restrict__ bb,
    float* __restrict__ xf, float* __restrict__ xb)
{
  int idx = blockIdx.x * 256 + threadIdx.x;
  int dir = blockIdx.y;
  if (idx >= LSEQ * DINNER) return;
  int l = idx / DINNER, c = idx % DINNER;
  const float* w = (dir ? wb : wf) + c * KCONV;
  float acc = (dir ? bb : bf)[c];
#pragma unroll
  for (int k = 0; k < KCONV; k++) {
    int ls = l - (KCONV - 1) + k;
    if (ls >= 0) {
      int lsrc = dir ? (LSEQ - 1 - ls) : ls;
      acc += w[k] * xz[(size_t)lsrc * (2 * DINNER) + c];
    }
  }
  float sv = acc / (1.f + __expf(-acc));
  (dir ? xb : xf)[idx] = sv;
}

// ---------------- chunked selective scan ----------------
// block = 256 threads = 16 chunks x 16 channels. blockIdx.x over DINNER/16.
// h_t = exp(delta_t * A) * h_{t-1} + delta_t * x_t * B_t ; y = sum_s h*C + D*x
__global__ __launch_bounds__(256) void scan_k(
    const float* __restrict__ xc,     // [L, DINNER] conv+silu output
    const float* __restrict__ delta,  // [L, DINNER]
    const float* __restrict__ dbc,    // [L, DBC]; Bm at [DRANK..), Cm at [DRANK+DSTATE..)
    const float* __restrict__ A_log,  // [DINNER, DSTATE]
    const float* __restrict__ Dvec,   // [DINNER]
    float* __restrict__ ycat,         // [L, 2*DINNER]
    int col_off)
{
  __shared__ float sP[16 * 16 * 16];
  __shared__ float sQ[16 * 16 * 16];
  const int tid = threadIdx.x;
  const int c = tid >> 4;       // chunk 0..15
  const int dl = tid & 15;      // channel-local
  const int d = blockIdx.x * 16 + dl;
  const int CH = LSEQ / 16;     // 64

  float Aa[DSTATE];
#pragma unroll
  for (int s = 0; s < DSTATE; s++) Aa[s] = -__expf(A_log[(size_t)d * DSTATE + s]);

  // phase 1: per-chunk affine summary (prod a, local q)
  float aP[DSTATE], q[DSTATE];
#pragma unroll
  for (int s = 0; s < DSTATE; s++) { aP[s] = 1.f; q[s] = 0.f; }
  const int l0 = c * CH;
  for (int i = 0; i < CH; i++) {
    int l = l0 + i;
    float dt = delta[(size_t)l * DINNER + d];
    float dx = dt * xc[(size_t)l * DINNER + d];
    const float* bm = dbc + (size_t)l * DBC + DRANK;
#pragma unroll
    for (int s = 0; s < DSTATE; s++) {
      float a = __expf(dt * Aa[s]);
      q[s] = a * q[s] + dx * bm[s];
      aP[s] *= a;
    }
  }
#pragma unroll
  for (int s = 0; s < DSTATE; s++) {
    sP[(c * 16 + dl) * 16 + s] = aP[s];
    sQ[(c * 16 + dl) * 16 + s] = q[s];
  }
  __syncthreads();

  // phase 2: serial combine across chunks; write h0 (carry-in) back into sP
  {
    const int d2 = tid >> 4, s2 = tid & 15;
    float h = 0.f;
    for (int cc = 0; cc < 16; cc++) {
      int idx = (cc * 16 + d2) * 16 + s2;
      float a = sP[idx], qq = sQ[idx];
      sP[idx] = h;
      h = a * h + qq;
    }
  }
  __syncthreads();

  // phase 3: replay with correct carry-in, emit y
  float hs[DSTATE];
#pragma unroll
  for (int s = 0; s < DSTATE; s++) hs[s] = sP[(c * 16 + dl) * 16 + s];
  const float Dd = Dvec[d];
  for (int i = 0; i < CH; i++) {
    int l = l0 + i;
    float dt = delta[(size_t)l * DINNER + d];
    float xv = xc[(size_t)l * DINNER + d];
    float dx = dt * xv;
    const float* bm = dbc + (size_t)l * DBC + DRANK;
    const float* cm = bm + DSTATE;
    float y = 0.f;
#pragma unroll
    for (int s = 0; s < DSTATE; s++) {
      float a = __expf(dt * Aa[s]);
      hs[s] = a * hs[s] + dx * bm[s];
      y += hs[s] * cm[s];
    }
    ycat[(size_t)l * (2 * DINNER) + col_off + d] = y + Dd * xv;
  }
}

// ---------------- row softmax (in-place) ----------------
__global__ __launch_bounds__(256) void softmax_k(float* __restrict__ S) {
  int row = blockIdx.x, tid = threadIdx.x;
  __shared__ float buf[LSEQ];
  __shared__ float red[256];
  float* r = S + (size_t)row * LSEQ;
  float m = -1e30f;
  for (int j = tid; j < LSEQ; j += 256) { float v = r[j]; buf[j] = v; m = fmaxf(m, v); }
  red[tid] = m; __syncthreads();
  for (int s = 128; s > 0; s >>= 1) { if (tid < s) red[tid] = fmaxf(red[tid], red[tid + s]); __syncthreads(); }
  m = red[0];
  __syncthreads();
  float sum = 0.f;
  for (int j = tid; j < LSEQ; j += 256) { float e = __expf(buf[j] - m); buf[j] = e; sum += e; }
  red[tid] = sum; __syncthreads();
  for (int s = 128; s > 0; s >>= 1) { if (tid < s) red[tid] += red[tid + s]; __syncthreads(); }
  float inv = 1.f / red[0];
  for (int j = tid; j < LSEQ; j += 256) r[j] = buf[j] * inv;
}

// ---------------- g = y2 * silu(z) ----------------
__global__ __launch_bounds__(256) void silumul_k(const float* __restrict__ y2,
                                                 const float* __restrict__ xz,
                                                 float* __restrict__ g) {
  int idx = blockIdx.x * 256 + threadIdx.x;
  if (idx >= LSEQ * DINNER) return;
  int l = idx / DINNER, d = idx % DINNER;
  float z = xz[(size_t)l * (2 * DINNER) + DINNER + d];
  float s = z / (1.f + __expf(-z));
  g[idx] = y2[idx] * s;
}

extern "C" void kernel_launch(void* const* d_in, const int* in_sizes, int n_in,
                              void* d_out, int out_size, void* d_ws, size_t ws_size,
                              hipStream_t stream) {
  const float* in_x      = (const float*)d_in[0];
  const float* norm_w    = (const float*)d_in[1];
  const float* in_proj_w = (const float*)d_in[2];
  const float* conv_f_w  = (const float*)d_in[3];
  const float* conv_f_b  = (const float*)d_in[4];
  const float* conv_b_w  = (const float*)d_in[5];
  const float* conv_b_b  = (const float*)d_in[6];
  const float* xproj_f_w = (const float*)d_in[7];
  const float* xproj_b_w = (const float*)d_in[8];
  const float* dt_f_w    = (const float*)d_in[9];
  const float* dt_f_b    = (const float*)d_in[10];
  const float* dt_b_w    = (const float*)d_in[11];
  const float* dt_b_b    = (const float*)d_in[12];
  const float* A_log_f   = (const float*)d_in[13];
  const float* D_f       = (const float*)d_in[14];
  const float* A_log_b   = (const float*)d_in[15];
  const float* D_b       = (const float*)d_in[16];
  const float* out_w     = (const float*)d_in[17];
  const float* token_wA  = (const float*)d_in[18];
  const float* token_wV  = (const float*)d_in[19];
  const float* pro_w     = (const float*)d_in[20];
  const float* pro_b     = (const float*)d_in[21];

  float* ws = (float*)d_ws;
  float* xbuf = ws; ws += LSEQ * DMODEL;
  float* xn   = ws; ws += LSEQ * DMODEL;
  float* xz   = ws; ws += LSEQ * 2 * DINNER;
  float* xf   = ws; ws += LSEQ * DINNER;
  float* xb   = ws; ws += LSEQ * DINNER;
  float* dbcf = ws; ws += LSEQ * DBC;
  float* dbcb = ws; ws += LSEQ * DBC;
  float* delf = ws; ws += LSEQ * DINNER;
  float* delb = ws; ws += LSEQ * DINNER;
  float* ycat = ws; ws += LSEQ * 2 * DINNER;
  float* ypro = ws; ws += LSEQ * DINNER;
  float* Smat = ws; ws += LSEQ * LSEQ;
  float* vv   = ws; ws += LSEQ * DINNER;
  float* y2   = ws; ws += LSEQ * DINNER;
  float* g    = ws; ws += LSEQ * DINNER;

  hipMemcpyAsync(xbuf, in_x, sizeof(float) * LSEQ * DMODEL,
                 hipMemcpyDeviceToDevice, stream);

  dim3 blk(256);
  for (int layer = 0; layer < NLAYER; layer++) {
    const float* nw  = norm_w    + (size_t)layer * DMODEL;
    const float* iw  = in_proj_w + (size_t)layer * 2 * DINNER * DMODEL;
    const float* cfw = conv_f_w  + (size_t)layer * DINNER * KCONV;
    const float* cfb = conv_f_b  + (size_t)layer * DINNER;
    const float* cbw = conv_b_w  + (size_t)layer * DINNER * KCONV;
    const float* cbb = conv_b_b  + (size_t)layer * DINNER;
    const float* xfw = xproj_f_w + (size_t)layer * DBC * DINNER;
    const float* xbw = xproj_b_w + (size_t)layer * DBC * DINNER;
    const float* dfw = dt_f_w    + (size_t)layer * DINNER * DRANK;
    const float* dfb = dt_f_b    + (size_t)layer * DINNER;
    const float* dbw = dt_b_w    + (size_t)layer * DINNER * DRANK;
    const float* dbb = dt_b_b    + (size_t)layer * DINNER;
    const float* Af  = A_log_f   + (size_t)layer * DINNER * DSTATE;
    const float* Df  = D_f       + (size_t)layer * DINNER;
    const float* Ab  = A_log_b   + (size_t)layer * DINNER * DSTATE;
    const float* Db  = D_b       + (size_t)layer * DINNER;
    const float* ow  = out_w     + (size_t)layer * DMODEL * DINNER;
    const float* wA  = token_wA  + (size_t)layer * LSEQ * DINNER;
    const float* wV  = token_wV  + (size_t)layer * DINNER * DINNER;
    const float* pw  = pro_w     + (size_t)layer * DINNER * 2 * DINNER;
    const float* pb  = pro_b     + (size_t)layer * DINNER;

    rmsnorm_k<<<LSEQ, blk, 0, stream>>>(xbuf, nw, xn);

    // xz = xn @ in_w^T          [1024, 3072] k=768
    gemm_k<0, 0><<<dim3((2 * DINNER) / BN, LSEQ / BM), blk, 0, stream>>>(
        xn, DMODEL, iw, DMODEL, xz, 2 * DINNER, LSEQ, 2 * DINNER, DMODEL,
        nullptr, nullptr, 0);

    conv_silu_k<<<dim3((LSEQ * DINNER) / 256, 2), blk, 0, stream>>>(
        xz, cfw, cfb, cbw, cbb, xf, xb);

    // dbc = x @ xproj^T         [1024, 80] k=1536
    gemm_k<0, 0><<<dim3((DBC + BN - 1) / BN, LSEQ / BM), blk, 0, stream>>>(
        xf, DINNER, xfw, DINNER, dbcf, DBC, LSEQ, DBC, DINNER, nullptr, nullptr, 0);
    gemm_k<0, 0><<<dim3((DBC + BN - 1) / BN, LSEQ / BM), blk, 0, stream>>>(
        xb, DINNER, xbw, DINNER, dbcb, DBC, LSEQ, DBC, DINNER, nullptr, nullptr, 0);

    // delta = softplus(dlt @ dt_w^T + dt_b)   [1024, 1536] k=48
    gemm_k<0, 3><<<dim3(DINNER / BN, LSEQ / BM), blk, 0, stream>>>(
        dbcf, DBC, dfw, DRANK, delf, DINNER, LSEQ, DINNER, DRANK, dfb, nullptr, 0);
    gemm_k<0, 3><<<dim3(DINNER / BN, LSEQ / BM), blk, 0, stream>>>(
        dbcb, DBC, dbw, DRANK, delb, DINNER, LSEQ, DINNER, DRANK, dbb, nullptr, 0);

    scan_k<<<DINNER / 16, blk, 0, stream>>>(xf, delf, dbcf, Af, Df, ycat, 0);
    scan_k<<<DINNER / 16, blk, 0, stream>>>(xb, delb, dbcb, Ab, Db, ycat, DINNER);

    // ypro = ycat @ pro_w^T + pro_b     [1024, 1536] k=3072
    gemm_k<0, 1><<<dim3(DINNER / BN, LSEQ / BM), blk, 0, stream>>>(
        ycat, 2 * DINNER, pw, 2 * DINNER, ypro, DINNER, LSEQ, DINNER, 2 * DINNER,
        pb, nullptr, 0);

    // S[t,l] = wA[t,:] . ypro[l,:]      [1024, 1024] k=1536
    gemm_k<0, 0><<<dim3(LSEQ / BN, LSEQ / BM), blk, 0, stream>>>(
        wA, DINNER, ypro, DINNER, Smat, LSEQ, LSEQ, LSEQ, DINNER, nullptr, nullptr, 0);
    softmax_k<<<LSEQ, blk, 0, stream>>>(Smat);

    // vv = ypro @ wV                    [1024, 1536] k=1536 (NN)
    gemm_k<1, 0><<<dim3(DINNER / BN, LSEQ / BM), blk, 0, stream>>>(
        ypro, DINNER, wV, DINNER, vv, DINNER, LSEQ, DINNER, DINNER, nullptr, nullptr, 0);

    // y2 = S @ vv                       [1024, 1536] k=1024 (NN)
    gemm_k<1, 0><<<dim3(DINNER / BN, LSEQ / BM), blk, 0, stream>>>(
        Smat, LSEQ, vv, DINNER, y2, DINNER, LSEQ, DINNER, LSEQ, nullptr, nullptr, 0);

    silumul_k<<<(LSEQ * DINNER) / 256, blk, 0, stream>>>(y2, xz, g);

    // x_next = x + g @ out_w^T          [1024, 768] k=1536
    float* target = (layer == NLAYER - 1) ? (float*)d_out : xbuf;
    gemm_k<0, 4><<<dim3(DMODEL / BN, LSEQ / BM), blk, 0, stream>>>(
        g, DINNER, ow, DINNER, target, DMODEL, LSEQ, DMODEL, DINNER,
        nullptr, xbuf, DMODEL);
  }
}

// Round 2
// 1234.653 us; speedup vs baseline: 1.5533x; 1.5533x over previous
//
#include <hip/hip_runtime.h>
#include <hip/hip_bf16.h>
#include <math.h>

#define LSEQ 1024
#define DMODEL 768
#define DINNER 1536
#define DSTATE 16
#define DRANK 48
#define KCONV 4
#define NLAYER 2
#define DBC 80  // DRANK + 2*DSTATE

typedef __attribute__((ext_vector_type(8))) __bf16 bf16x8;
typedef __attribute__((ext_vector_type(4))) float f32x4;
typedef __attribute__((ext_vector_type(4))) unsigned short us4;

__device__ inline unsigned short f2bf(float f) {
  union { float f; unsigned u; } v; v.f = f;
  unsigned r = v.u + 0x7fffu + ((v.u >> 16) & 1u);  // RNE
  return (unsigned short)(r >> 16);
}

// ---------------- rmsnorm ----------------
__global__ __launch_bounds__(256) void rmsnorm_k(const float* __restrict__ x,
                                                 const float* __restrict__ w,
                                                 float* __restrict__ xn) {
  int row = blockIdx.x;
  int tid = threadIdx.x;
  const float* xr = x + (size_t)row * DMODEL;
  float ss = 0.f;
  for (int j = tid; j < DMODEL; j += 256) { float v = xr[j]; ss += v * v; }
  __shared__ float red[256];
  red[tid] = ss; __syncthreads();
  for (int s = 128; s > 0; s >>= 1) { if (tid < s) red[tid] += red[tid + s]; __syncthreads(); }
  float scale = rsqrtf(red[0] / (float)DMODEL + 1e-5f);
  float* outr = xn + (size_t)row * DMODEL;
  for (int j = tid; j < DMODEL; j += 256) outr[j] = xr[j] * scale * w[j];
}

// ---------------- MFMA bf16 GEMM (NT: A[M,K] fp32, B[N,K] fp32) ----------------
// C[m,n] = sum_k A[m,k]*B[n,k]  (both converted to bf16 in staging)
// EPI bit0: += bias[n]; bit2: += resid[m,n]
#define TBM 64
#define TBN 128
#define TBK 32
#define BKP 40  // padded row length (bf16 elems) -> 80B rows, 16B aligned

template<int EPI>
__global__ __launch_bounds__(256) void mgemm_k(
    const float* __restrict__ A, int lda,
    const float* __restrict__ B, int ldb,
    float* __restrict__ C, int ldc,
    int M, int N, int K,
    const float* __restrict__ bias,
    const float* __restrict__ resid, int ldr)
{
  __shared__ unsigned short As[TBM][BKP];
  __shared__ unsigned short Bs[TBN][BKP];
  const int tid = threadIdx.x;
  const int lane = tid & 63;
  const int wid = tid >> 6;          // 0..3
  const int wm = (wid >> 1) * 32;    // wave row offset
  const int wn = (wid & 1) * 64;     // wave col offset
  const int bm = blockIdx.y * TBM;
  const int bn = blockIdx.x * TBN;

  const int srow = tid >> 3;         // 0..31 staging row
  const int sk = (tid & 7) * 4;      // 0..28 staging k offset (float4)

  f32x4 acc[2][4];
#pragma unroll
  for (int i = 0; i < 2; i++)
#pragma unroll
    for (int j = 0; j < 4; j++) acc[i][j] = (f32x4){0.f, 0.f, 0.f, 0.f};

  float4 ra[2], rb[4];
  const float* Ab = A + (size_t)(bm + srow) * lda + sk;
  const float* Bb = B + (size_t)(bn + srow) * ldb + sk;

#define LOADT(k0) do { \
    ra[0] = *(const float4*)(Ab + (k0)); \
    ra[1] = *(const float4*)(Ab + 32 * (size_t)lda + (k0)); \
    rb[0] = *(const float4*)(Bb + (k0)); \
    rb[1] = *(const float4*)(Bb + 32 * (size_t)ldb + (k0)); \
    rb[2] = *(const float4*)(Bb + 64 * (size_t)ldb + (k0)); \
    rb[3] = *(const float4*)(Bb + 96 * (size_t)ldb + (k0)); \
  } while (0)

  LOADT(0);

  const int fr = lane & 15;
  const int fk = (lane >> 4) * 8;

  for (int k0 = 0; k0 < K; k0 += TBK) {
    __syncthreads();  // LDS from previous iteration fully consumed
#pragma unroll
    for (int i = 0; i < 2; i++) {
      us4 w; w[0] = f2bf(ra[i].x); w[1] = f2bf(ra[i].y);
      w[2] = f2bf(ra[i].z); w[3] = f2bf(ra[i].w);
      *(us4*)&As[srow + 32 * i][sk] = w;
    }
#pragma unroll
    for (int i = 0; i < 4; i++) {
      us4 w; w[0] = f2bf(rb[i].x); w[1] = f2bf(rb[i].y);
      w[2] = f2bf(rb[i].z); w[3] = f2bf(rb[i].w);
      *(us4*)&Bs[srow + 32 * i][sk] = w;
    }
    __syncthreads();
    if (k0 + TBK < K) LOADT(k0 + TBK);  // prefetch next tile; latency hides under MFMA

    bf16x8 af[2], bfr[4];
#pragma unroll
    for (int i = 0; i < 2; i++)
      af[i] = *reinterpret_cast<const bf16x8*>(&As[wm + i * 16 + fr][fk]);
#pragma unroll
    for (int j = 0; j < 4; j++)
      bfr[j] = *reinterpret_cast<const bf16x8*>(&Bs[wn + j * 16 + fr][fk]);
#pragma unroll
    for (int i = 0; i < 2; i++)
#pragma unroll
      for (int j = 0; j < 4; j++)
        acc[i][j] = __builtin_amdgcn_mfma_f32_16x16x32_bf16(af[i], bfr[j], acc[i][j], 0, 0, 0);
  }

  const int fq = lane >> 4;
#pragma unroll
  for (int i = 0; i < 2; i++) {
#pragma unroll
    for (int j = 0; j < 4; j++) {
      int col = bn + wn + j * 16 + fr;
      float bv = (EPI & 1) ? bias[col] : 0.f;
#pragma unroll
      for (int r = 0; r < 4; r++) {
        int row = bm + wm + i * 16 + fq * 4 + r;
        float v = acc[i][j][r] + bv;
        if (EPI & 4) v += resid[(size_t)row * ldr + col];
        C[(size_t)row * ldc + col] = v;
      }
    }
  }
}

// ---------------- fp32 transpose (out[c][r] = in[r][c]) ----------------
__global__ __launch_bounds__(256) void transpose_k(const float* __restrict__ in,
                                                   float* __restrict__ out,
                                                   int R, int C) {
  __shared__ float t[32][33];
  int c0 = blockIdx.x * 32, r0 = blockIdx.y * 32;
  int tx = threadIdx.x & 31, ty = threadIdx.x >> 5;
  for (int i = ty; i < 32; i += 8) t[i][tx] = in[(size_t)(r0 + i) * C + c0 + tx];
  __syncthreads();
  for (int i = ty; i < 32; i += 8) out[(size_t)(c0 + i) * R + r0 + tx] = t[tx][i];
}

// ---------------- fp32 tiled GEMM (kept for small precision-sensitive GEMMs) ----
// C[m,n] = sum_k A[m,k] * B(n,k); BLAYOUT 0: B [N,K]. EPI bit0 bias, bit1 softplus.
#define BM 64
#define BN 64
#define BK 16

template<int BLAYOUT, int EPI>
__global__ __launch_bounds__(256) void gemm_k(
    const float* __restrict__ A, int lda,
    const float* __restrict__ B, int ldb,
    float* __restrict__ C, int ldc,
    int M, int N, int K,
    const float* __restrict__ bias,
    const float* __restrict__ resid, int ldr)
{
  __shared__ float Asf[BK][BM];
  __shared__ float Bsf[BK][BN + 4];
  const int tid = threadIdx.x;
  const int bm = blockIdx.y * BM;
  const int bn = blockIdx.x * BN;
  const int ar = tid >> 2;
  const int ak = (tid & 3) << 2;
  const int ty = tid >> 4, tx = tid & 15;
  float acc[4][4] = {};

  for (int k0 = 0; k0 < K; k0 += BK) {
    float4 av = *(const float4*)(A + (size_t)(bm + ar) * lda + k0 + ak);
    float4 bv = make_float4(0.f, 0.f, 0.f, 0.f);
    if (bn + ar < N) bv = *(const float4*)(B + (size_t)(bn + ar) * ldb + k0 + ak);
    __syncthreads();
    Asf[ak + 0][ar] = av.x; Asf[ak + 1][ar] = av.y;
    Asf[ak + 2][ar] = av.z; Asf[ak + 3][ar] = av.w;
    Bsf[ak + 0][ar] = bv.x; Bsf[ak + 1][ar] = bv.y;
    Bsf[ak + 2][ar] = bv.z; Bsf[ak + 3][ar] = bv.w;
    __syncthreads();
#pragma unroll
    for (int kk = 0; kk < BK; kk++) {
      float4 a4 = *(const float4*)&Asf[kk][ty * 4];
      float4 b4 = *(const float4*)&Bsf[kk][tx * 4];
      float a[4] = {a4.x, a4.y, a4.z, a4.w};
      float b[4] = {b4.x, b4.y, b4.z, b4.w};
#pragma unroll
      for (int i = 0; i < 4; i++)
#pragma unroll
        for (int j = 0; j < 4; j++)
          acc[i][j] += a[i] * b[j];
    }
  }

#pragma unroll
  for (int i = 0; i < 4; i++) {
    int row = bm + ty * 4 + i;
#pragma unroll
    for (int j = 0; j < 4; j++) {
      int col = bn + tx * 4 + j;
      if (col < N) {
        float v = acc[i][j];
        if (EPI & 1) v += bias[col];
        if (EPI & 2) v = (v > 20.f) ? v : log1pf(__expf(v));
        C[(size_t)row * ldc + col] = v;
      }
    }
  }
}

// ---------------- causal depthwise conv + silu (both directions) ----------------
__global__ __launch_bounds__(256) void conv_silu_k(
    const float* __restrict__ xz,
    const float* __restrict__ wf, const float* __restrict__ bf,
    const float* __restrict__ wb, const float* __restrict__ bb,
    float* __restrict__ xf, float* __restrict__ xb)
{
  int idx = blockIdx.x * 256 + threadIdx.x;
  int dir = blockIdx.y;
  if (idx >= LSEQ * DINNER) return;
  int l = idx / DINNER, c = idx % DINNER;
  const float* w = (dir ? wb : wf) + c * KCONV;
  float acc = (dir ? bb : bf)[c];
#pragma unroll
  for (int k = 0; k < KCONV; k++) {
    int ls = l - (KCONV - 1) + k;
    if (ls >= 0) {
      int lsrc = dir ? (LSEQ - 1 - ls) : ls;
      acc += w[k] * xz[(size_t)lsrc * (2 * DINNER) + c];
    }
  }
  float sv = acc / (1.f + __expf(-acc));
  (dir ? xb : xf)[idx] = sv;
}

// ---------------- chunked selective scan ----------------
__global__ __launch_bounds__(256) void scan_k(
    const float* __restrict__ xc,
    const float* __restrict__ delta,
    const float* __restrict__ dbc,
    const float* __restrict__ A_log,
    const float* __restrict__ Dvec,
    float* __restrict__ ycat,
    int col_off)
{
  __shared__ float sP[16 * 16 * 16];
  __shared__ float sQ[16 * 16 * 16];
  const int tid = threadIdx.x;
  const int c = tid >> 4;
  const int dl = tid & 15;
  const int d = blockIdx.x * 16 + dl;
  const int CH = LSEQ / 16;

  float Aa[DSTATE];
#pragma unroll
  for (int s = 0; s < DSTATE; s++) Aa[s] = -__expf(A_log[(size_t)d * DSTATE + s]);

  float aP[DSTATE], q[DSTATE];
#pragma unroll
  for (int s = 0; s < DSTATE; s++) { aP[s] = 1.f; q[s] = 0.f; }
  const int l0 = c * CH;
  for (int i = 0; i < CH; i++) {
    int l = l0 + i;
    float dt = delta[(size_t)l * DINNER + d];
    float dx = dt * xc[(size_t)l * DINNER + d];
    const float* bm = dbc + (size_t)l * DBC + DRANK;
#pragma unroll
    for (int s = 0; s < DSTATE; s++) {
      float a = __expf(dt * Aa[s]);
      q[s] = a * q[s] + dx * bm[s];
      aP[s] *= a;
    }
  }
#pragma unroll
  for (int s = 0; s < DSTATE; s++) {
    sP[(c * 16 + dl) * 16 + s] = aP[s];
    sQ[(c * 16 + dl) * 16 + s] = q[s];
  }
  __syncthreads();

  {
    const int d2 = tid >> 4, s2 = tid & 15;
    float h = 0.f;
    for (int cc = 0; cc < 16; cc++) {
      int idx = (cc * 16 + d2) * 16 + s2;
      float a = sP[idx], qq = sQ[idx];
      sP[idx] = h;
      h = a * h + qq;
    }
  }
  __syncthreads();

  float hs[DSTATE];
#pragma unroll
  for (int s = 0; s < DSTATE; s++) hs[s] = sP[(c * 16 + dl) * 16 + s];
  const float Dd = Dvec[d];
  for (int i = 0; i < CH; i++) {
    int l = l0 + i;
    float dt = delta[(size_t)l * DINNER + d];
    float xv = xc[(size_t)l * DINNER + d];
    float dx = dt * xv;
    const float* bm = dbc + (size_t)l * DBC + DRANK;
    const float* cm = bm + DSTATE;
    float y = 0.f;
#pragma unroll
    for (int s = 0; s < DSTATE; s++) {
      float a = __expf(dt * Aa[s]);
      hs[s] = a * hs[s] + dx * bm[s];
      y += hs[s] * cm[s];
    }
    ycat[(size_t)l * (2 * DINNER) + col_off + d] = y + Dd * xv;
  }
}

// ---------------- row softmax (in-place) ----------------
__global__ __launch_bounds__(256) void softmax_k(float* __restrict__ S) {
  int row = blockIdx.x, tid = threadIdx.x;
  __shared__ float buf[LSEQ];
  __shared__ float red[256];
  float* r = S + (size_t)row * LSEQ;
  float m = -1e30f;
  for (int j = tid; j < LSEQ; j += 256) { float v = r[j]; buf[j] = v; m = fmaxf(m, v); }
  red[tid] = m; __syncthreads();
  for (int s = 128; s > 0; s >>= 1) { if (tid < s) red[tid] = fmaxf(red[tid], red[tid + s]); __syncthreads(); }
  m = red[0];
  __syncthreads();
  float sum = 0.f;
  for (int j = tid; j < LSEQ; j += 256) { float e = __expf(buf[j] - m); buf[j] = e; sum += e; }
  red[tid] = sum; __syncthreads();
  for (int s = 128; s > 0; s >>= 1) { if (tid < s) red[tid] += red[tid + s]; __syncthreads(); }
  float inv = 1.f / red[0];
  for (int j = tid; j < LSEQ; j += 256) r[j] = buf[j] * inv;
}

// ---------------- g = y2 * silu(z) ----------------
__global__ __launch_bounds__(256) void silumul_k(const float* __restrict__ y2,
                                                 const float* __restrict__ xz,
                                                 float* __restrict__ g) {
  int idx = blockIdx.x * 256 + threadIdx.x;
  if (idx >= LSEQ * DINNER) return;
  int l = idx / DINNER, d = idx % DINNER;
  float z = xz[(size_t)l * (2 * DINNER) + DINNER + d];
  float s = z / (1.f + __expf(-z));
  g[idx] = y2[idx] * s;
}

extern "C" void kernel_launch(void* const* d_in, const int* in_sizes, int n_in,
                              void* d_out, int out_size, void* d_ws, size_t ws_size,
                              hipStream_t stream) {
  const float* in_x      = (const float*)d_in[0];
  const float* norm_w    = (const float*)d_in[1];
  const float* in_proj_w = (const float*)d_in[2];
  const float* conv_f_w  = (const float*)d_in[3];
  const float* conv_f_b  = (const float*)d_in[4];
  const float* conv_b_w  = (const float*)d_in[5];
  const float* conv_b_b  = (const float*)d_in[6];
  const float* xproj_f_w = (const float*)d_in[7];
  const float* xproj_b_w = (const float*)d_in[8];
  const float* dt_f_w    = (const float*)d_in[9];
  const float* dt_f_b    = (const float*)d_in[10];
  const float* dt_b_w    = (const float*)d_in[11];
  const float* dt_b_b    = (const float*)d_in[12];
  const float* A_log_f   = (const float*)d_in[13];
  const float* D_f       = (const float*)d_in[14];
  const float* A_log_b   = (const float*)d_in[15];
  const float* D_b       = (const float*)d_in[16];
  const float* out_w     = (const float*)d_in[17];
  const float* token_wA  = (const float*)d_in[18];
  const float* token_wV  = (const float*)d_in[19];
  const float* pro_w     = (const float*)d_in[20];
  const float* pro_b     = (const float*)d_in[21];

  float* ws = (float*)d_ws;
  float* xbuf = ws; ws += LSEQ * DMODEL;
  float* xn   = ws; ws += LSEQ * DMODEL;
  float* xz   = ws; ws += LSEQ * 2 * DINNER;
  float* xf   = ws; ws += LSEQ * DINNER;   // also reused as wVT (needs DINNER*DINNER <= 2*LSEQ*DINNER with xb)
  float* xb   = ws; ws += LSEQ * DINNER;
  float* dbcf = ws; ws += LSEQ * DBC;
  float* dbcb = ws; ws += LSEQ * DBC;
  float* delf = ws; ws += LSEQ * DINNER;   // also reused as vvT [DINNER][LSEQ]
  float* delb = ws; ws += LSEQ * DINNER;
  float* ycat = ws; ws += LSEQ * 2 * DINNER;
  float* ypro = ws; ws += LSEQ * DINNER;
  float* Smat = ws; ws += LSEQ * LSEQ;
  float* vv   = ws; ws += LSEQ * DINNER;
  float* y2   = ws; ws += LSEQ * DINNER;
  float* g    = ws; ws += LSEQ * DINNER;

  float* wVT = xf;    // [DINNER][DINNER] fits in xf+xb (2*LSEQ*DINNER = 3.1M >= 2.36M); xf/xb dead after scans
  float* vvT = delf;  // [DINNER][LSEQ] = LSEQ*DINNER exactly; delf dead after scans

  hipMemcpyAsync(xbuf, in_x, sizeof(float) * LSEQ * DMODEL,
                 hipMemcpyDeviceToDevice, stream);

  dim3 blk(256);
  for (int layer = 0; layer < NLAYER; layer++) {
    const float* nw  = norm_w    + (size_t)layer * DMODEL;
    const float* iw  = in_proj_w + (size_t)layer * 2 * DINNER * DMODEL;
    const float* cfw = conv_f_w  + (size_t)layer * DINNER * KCONV;
    const float* cfb = conv_f_b  + (size_t)layer * DINNER;
    const float* cbw = conv_b_w  + (size_t)layer * DINNER * KCONV;
    const float* cbb = conv_b_b  + (size_t)layer * DINNER;
    const float* xfw = xproj_f_w + (size_t)layer * DBC * DINNER;
    const float* xbw = xproj_b_w + (size_t)layer * DBC * DINNER;
    const float* dfw = dt_f_w    + (size_t)layer * DINNER * DRANK;
    const float* dfb = dt_f_b    + (size_t)layer * DINNER;
    const float* dbw = dt_b_w    + (size_t)layer * DINNER * DRANK;
    const float* dbb = dt_b_b    + (size_t)layer * DINNER;
    const float* Af  = A_log_f   + (size_t)layer * DINNER * DSTATE;
    const float* Df  = D_f       + (size_t)layer * DINNER;
    const float* Ab  = A_log_b   + (size_t)layer * DINNER * DSTATE;
    const float* Db  = D_b       + (size_t)layer * DINNER;
    const float* ow  = out_w     + (size_t)layer * DMODEL * DINNER;
    const float* wA  = token_wA  + (size_t)layer * LSEQ * DINNER;
    const float* wV  = token_wV  + (size_t)layer * DINNER * DINNER;
    const float* pw  = pro_w     + (size_t)layer * DINNER * 2 * DINNER;
    const float* pb  = pro_b     + (size_t)layer * DINNER;

    rmsnorm_k<<<LSEQ, blk, 0, stream>>>(xbuf, nw, xn);

    // xz = xn @ in_w^T   [1024, 3072] k=768  (MFMA)
    mgemm_k<0><<<dim3((2 * DINNER) / TBN, LSEQ / TBM), blk, 0, stream>>>(
        xn, DMODEL, iw, DMODEL, xz, 2 * DINNER, LSEQ, 2 * DINNER, DMODEL,
        nullptr, nullptr, 0);

    conv_silu_k<<<dim3((LSEQ * DINNER) / 256, 2), blk, 0, stream>>>(
        xz, cfw, cfb, cbw, cbb, xf, xb);

    // dbc = x @ xproj^T  [1024, 80] k=1536  (fp32, precision-sensitive path)
    gemm_k<0, 0><<<dim3((DBC + BN - 1) / BN, LSEQ / BM), blk, 0, stream>>>(
        xf, DINNER, xfw, DINNER, dbcf, DBC, LSEQ, DBC, DINNER, nullptr, nullptr, 0);
    gemm_k<0, 0><<<dim3((DBC + BN - 1) / BN, LSEQ / BM), blk, 0, stream>>>(
        xb, DINNER, xbw, DINNER, dbcb, DBC, LSEQ, DBC, DINNER, nullptr, nullptr, 0);

    // delta = softplus(dlt @ dt_w^T + dt_b)  [1024, 1536] k=48 (fp32)
    gemm_k<0, 3><<<dim3(DINNER / BN, LSEQ / BM), blk, 0, stream>>>(
        dbcf, DBC, dfw, DRANK, delf, DINNER, LSEQ, DINNER, DRANK, dfb, nullptr, 0);
    gemm_k<0, 3><<<dim3(DINNER / BN, LSEQ / BM), blk, 0, stream>>>(
        dbcb, DBC, dbw, DRANK, delb, DINNER, LSEQ, DINNER, DRANK, dbb, nullptr, 0);

    scan_k<<<DINNER / 16, blk, 0, stream>>>(xf, delf, dbcf, Af, Df, ycat, 0);
    scan_k<<<DINNER / 16, blk, 0, stream>>>(xb, delb, dbcb, Ab, Db, ycat, DINNER);

    // ypro = ycat @ pro_w^T + pro_b   [1024, 1536] k=3072 (MFMA)
    mgemm_k<1><<<dim3(DINNER / TBN, LSEQ / TBM), blk, 0, stream>>>(
        ycat, 2 * DINNER, pw, 2 * DINNER, ypro, DINNER, LSEQ, DINNER, 2 * DINNER,
        pb, nullptr, 0);

    // S[t,l] = wA[t,:] . ypro[l,:]    [1024, 1024] k=1536 (MFMA, native NT)
    mgemm_k<0><<<dim3(LSEQ / TBN, LSEQ / TBM), blk, 0, stream>>>(
        wA, DINNER, ypro, DINNER, Smat, LSEQ, LSEQ, LSEQ, DINNER,
        nullptr, nullptr, 0);
    softmax_k<<<LSEQ, blk, 0, stream>>>(Smat);

    // wVT[e][d] = wV[d][e]; vv = ypro @ wV  -> NT with B = wVT  [1024,1536] k=1536
    transpose_k<<<dim3(DINNER / 32, DINNER / 32), blk, 0, stream>>>(wV, wVT, DINNER, DINNER);
    mgemm_k<0><<<dim3(DINNER / TBN, LSEQ / TBM), blk, 0, stream>>>(
        ypro, DINNER, wVT, DINNER, vv, DINNER, LSEQ, DINNER, DINNER,
        nullptr, nullptr, 0);

    // vvT[e][l] = vv[l][e]; y2 = S @ vv -> NT with B = vvT  [1024,1536] k=1024
    transpose_k<<<dim3(DINNER / 32, LSEQ / 32), blk, 0, stream>>>(vv, vvT, LSEQ, DINNER);
    mgemm_k<0><<<dim3(DINNER / TBN, LSEQ / TBM), blk, 0, stream>>>(
        Smat, LSEQ, vvT, LSEQ, y2, DINNER, LSEQ, DINNER, LSEQ,
        nullptr, nullptr, 0);

    silumul_k<<<(LSEQ * DINNER) / 256, blk, 0, stream>>>(y2, xz, g);

    // x_next = x + g @ out_w^T   [1024, 768] k=1536 (MFMA, residual epilogue)
    float* target = (layer == NLAYER - 1) ? (float*)d_out : xbuf;
    mgemm_k<4><<<dim3(DMODEL / TBN, LSEQ / TBM), blk, 0, stream>>>(
        g, DINNER, ow, DINNER, target, DMODEL, LSEQ, DMODEL, DINNER,
        nullptr, xbuf, DMODEL);
  }
}

// Round 3
// 1108.542 us; speedup vs baseline: 1.7300x; 1.1138x over previous
//
#include <hip/hip_runtime.h>
#include <hip/hip_bf16.h>
#include <math.h>
#include <stdint.h>

#define LSEQ 1024
#define DMODEL 768
#define DINNER 1536
#define DSTATE 16
#define DRANK 48
#define KCONV 4
#define NLAYER 2
#define DBC 80  // DRANK + 2*DSTATE

typedef unsigned short u16;
typedef __attribute__((ext_vector_type(8))) __bf16 bf16x8;
typedef __attribute__((ext_vector_type(4))) float f32x4;
typedef __attribute__((ext_vector_type(4))) unsigned short us4;

__device__ __forceinline__ u16 f2bf(float f) {
  union { float f; unsigned u; } v; v.f = f;
  unsigned r = v.u + 0x7fffu + ((v.u >> 16) & 1u);  // RNE
  return (u16)(r >> 16);
}

// CK-style addrspace casts for global_load_lds (direct HBM->LDS DMA, 16B/lane)
__device__ __forceinline__ void gload16(const void* g, void* l) {
  auto gp = reinterpret_cast<const __attribute__((address_space(1))) uint32_t*>(
      reinterpret_cast<uintptr_t>(g));
  auto lp = reinterpret_cast<__attribute__((address_space(3))) uint32_t*>(
      reinterpret_cast<uintptr_t>(l));
  __builtin_amdgcn_global_load_lds(gp, lp, 16, 0, 0);
}

// ---------------- fp32 -> bf16 flat convert ----------------
__global__ __launch_bounds__(256) void cvt_k(const float* __restrict__ in,
                                             u16* __restrict__ out, int n4) {
  int i = blockIdx.x * 256 + threadIdx.x;
  if (i >= n4) return;
  float4 v = ((const float4*)in)[i];
  us4 o; o[0] = f2bf(v.x); o[1] = f2bf(v.y); o[2] = f2bf(v.z); o[3] = f2bf(v.w);
  ((us4*)out)[i] = o;
}

// ---------------- fp32 -> bf16 transpose-convert (out[c][r] = in[r][c]) -------
__global__ __launch_bounds__(256) void transcvt_k(const float* __restrict__ in,
                                                  u16* __restrict__ out,
                                                  int R, int C) {
  __shared__ float t[32][33];
  int c0 = blockIdx.x * 32, r0 = blockIdx.y * 32;
  int tx = threadIdx.x & 31, ty = threadIdx.x >> 5;
  for (int i = ty; i < 32; i += 8) t[i][tx] = in[(size_t)(r0 + i) * C + c0 + tx];
  __syncthreads();
  for (int i = ty; i < 32; i += 8)
    out[(size_t)(c0 + i) * R + r0 + tx] = f2bf(t[tx][i]);
}

// ---------------- bf16 -> bf16 transpose ----------------
__global__ __launch_bounds__(256) void transpose16_k(const u16* __restrict__ in,
                                                     u16* __restrict__ out,
                                                     int R, int C) {
  __shared__ u16 t[32][34];
  int c0 = blockIdx.x * 32, r0 = blockIdx.y * 32;
  int tx = threadIdx.x & 31, ty = threadIdx.x >> 5;
  for (int i = ty; i < 32; i += 8) t[i][tx] = in[(size_t)(r0 + i) * C + c0 + tx];
  __syncthreads();
  for (int i = ty; i < 32; i += 8)
    out[(size_t)(c0 + i) * R + r0 + tx] = t[tx][i];
}

// ---------------- rmsnorm (bf16 out) ----------------
__global__ __launch_bounds__(256) void rmsnorm_k(const float* __restrict__ x,
                                                 const float* __restrict__ w,
                                                 u16* __restrict__ xn) {
  int row = blockIdx.x;
  int tid = threadIdx.x;
  const float* xr = x + (size_t)row * DMODEL;
  float ss = 0.f;
  for (int j = tid; j < DMODEL; j += 256) { float v = xr[j]; ss += v * v; }
  __shared__ float red[256];
  red[tid] = ss; __syncthreads();
  for (int s = 128; s > 0; s >>= 1) { if (tid < s) red[tid] += red[tid + s]; __syncthreads(); }
  float scale = rsqrtf(red[0] / (float)DMODEL + 1e-5f);
  u16* outr = xn + (size_t)row * DMODEL;
  for (int j = tid; j < DMODEL; j += 256) outr[j] = f2bf(xr[j] * scale * w[j]);
}

// ---------------- MFMA bf16 GEMM, m97 structure ----------------
// C[m,n] = sum_k A[m,k]*B[n,k]; A [M,K] bf16, B [N,K] bf16 (NT).
// 128x128 tile, BK=32, 4 waves each 64x64 (4x4 frags of 16x16x32).
// global_load_lds staging, double-buffered LDS, 1 barrier per K-step.
// EPI bit0: +bias[n]; bit2: +resid fp32; bit3: bf16 output.
template<int EPI>
__global__ __launch_bounds__(256) void mgemm_k(
    const u16* __restrict__ A, int lda,
    const u16* __restrict__ B, int ldb,
    void* __restrict__ Cv, int ldc, int K,
    const float* __restrict__ bias,
    const float* __restrict__ resid, int ldr)
{
  __shared__ u16 As[2][128 * 32];
  __shared__ u16 Bs[2][128 * 32];
  const int tid = threadIdx.x;
  const int lane = tid & 63;
  const int wid = tid >> 6;
  const int bm = blockIdx.y * 128;
  const int bn = blockIdx.x * 128;
  const int wm = (wid >> 1) * 64;
  const int wn = (wid & 1) * 64;

  // DMA staging map: chunk c (0,1), wave wid, lane L -> LDS bytes
  // [c*4096 + wid*1024 + L*16) == row (c*64 + wid*16 + L/4), kcol (L%4)*8
  const int r0 = wid * 16 + (lane >> 2);
  const int koff = (lane & 3) * 8;
  const u16* Ag0 = A + (size_t)(bm + r0) * lda + koff;
  const u16* Ag1 = Ag0 + (size_t)64 * lda;
  const u16* Bg0 = B + (size_t)(bn + r0) * ldb + koff;
  const u16* Bg1 = Bg0 + (size_t)64 * ldb;
  const int lb0 = wid * 512;         // ushort offset of this wave's chunk-0
  const int lb1 = 2048 + wid * 512;  // chunk-1

  f32x4 acc[4][4];
#pragma unroll
  for (int i = 0; i < 4; i++)
#pragma unroll
    for (int j = 0; j < 4; j++) acc[i][j] = (f32x4){0.f, 0.f, 0.f, 0.f};

#define STAGE(buf, k0) do { \
    gload16(Ag0 + (k0), &As[buf][lb0]); \
    gload16(Ag1 + (k0), &As[buf][lb1]); \
    gload16(Bg0 + (k0), &Bs[buf][lb0]); \
    gload16(Bg1 + (k0), &Bs[buf][lb1]); \
  } while (0)

  STAGE(0, 0);
  const int nk = K >> 5;
  const int fr = lane & 15;
  const int fks = (lane >> 4) * 8;

  for (int t = 0; t < nk; t++) {
    const int buf = t & 1;
    __syncthreads();  // compiler drains vmcnt(0): buf's DMA landed; buf^1 free
    if (t + 1 < nk) STAGE(buf ^ 1, (t + 1) << 5);
    bf16x8 af[4], bfv[4];
#pragma unroll
    for (int i = 0; i < 4; i++)
      af[i] = *reinterpret_cast<const bf16x8*>(&As[buf][(wm + i * 16 + fr) * 32 + fks]);
#pragma unroll
    for (int j = 0; j < 4; j++)
      bfv[j] = *reinterpret_cast<const bf16x8*>(&Bs[buf][(wn + j * 16 + fr) * 32 + fks]);
#pragma unroll
    for (int i = 0; i < 4; i++)
#pragma unroll
      for (int j = 0; j < 4; j++)
        acc[i][j] = __builtin_amdgcn_mfma_f32_16x16x32_bf16(af[i], bfv[j], acc[i][j], 0, 0, 0);
  }
#undef STAGE

  const int fq = lane >> 4;
#pragma unroll
  for (int i = 0; i < 4; i++) {
#pragma unroll
    for (int j = 0; j < 4; j++) {
      const int col = bn + wn + j * 16 + fr;
      const int row0 = bm + wm + i * 16 + fq * 4;
      float bv = (EPI & 1) ? bias[col] : 0.f;
#pragma unroll
      for (int r = 0; r < 4; r++) {
        float v = acc[i][j][r] + bv;
        if (EPI & 4) v += resid[(size_t)(row0 + r) * ldr + col];
        if (EPI & 8) ((u16*)Cv)[(size_t)(row0 + r) * ldc + col] = f2bf(v);
        else         ((float*)Cv)[(size_t)(row0 + r) * ldc + col] = v;
      }
    }
  }
}

// ---------------- fp32 tiled GEMM (small precision-sensitive GEMMs) ----------
#define BM 64
#define BN 64
#define BK 16

template<int EPI>  // bit0 bias, bit1 softplus
__global__ __launch_bounds__(256) void gemm_k(
    const float* __restrict__ A, int lda,
    const float* __restrict__ B, int ldb,
    float* __restrict__ C, int ldc,
    int M, int N, int K,
    const float* __restrict__ bias)
{
  __shared__ float Asf[BK][BM];
  __shared__ float Bsf[BK][BN + 4];
  const int tid = threadIdx.x;
  const int bm = blockIdx.y * BM;
  const int bn = blockIdx.x * BN;
  const int ar = tid >> 2;
  const int ak = (tid & 3) << 2;
  const int ty = tid >> 4, tx = tid & 15;
  float acc[4][4] = {};

  for (int k0 = 0; k0 < K; k0 += BK) {
    float4 av = *(const float4*)(A + (size_t)(bm + ar) * lda + k0 + ak);
    float4 bv = make_float4(0.f, 0.f, 0.f, 0.f);
    if (bn + ar < N) bv = *(const float4*)(B + (size_t)(bn + ar) * ldb + k0 + ak);
    __syncthreads();
    Asf[ak + 0][ar] = av.x; Asf[ak + 1][ar] = av.y;
    Asf[ak + 2][ar] = av.z; Asf[ak + 3][ar] = av.w;
    Bsf[ak + 0][ar] = bv.x; Bsf[ak + 1][ar] = bv.y;
    Bsf[ak + 2][ar] = bv.z; Bsf[ak + 3][ar] = bv.w;
    __syncthreads();
#pragma unroll
    for (int kk = 0; kk < BK; kk++) {
      float4 a4 = *(const float4*)&Asf[kk][ty * 4];
      float4 b4 = *(const float4*)&Bsf[kk][tx * 4];
      float a[4] = {a4.x, a4.y, a4.z, a4.w};
      float b[4] = {b4.x, b4.y, b4.z, b4.w};
#pragma unroll
      for (int i = 0; i < 4; i++)
#pragma unroll
        for (int j = 0; j < 4; j++)
          acc[i][j] += a[i] * b[j];
    }
  }

#pragma unroll
  for (int i = 0; i < 4; i++) {
    int row = bm + ty * 4 + i;
#pragma unroll
    for (int j = 0; j < 4; j++) {
      int col = bn + tx * 4 + j;
      if (col < N) {
        float v = acc[i][j];
        if (EPI & 1) v += bias[col];
        if (EPI & 2) v = (v > 20.f) ? v : log1pf(__expf(v));
        C[(size_t)row * ldc + col] = v;
      }
    }
  }
}

// ---------------- causal depthwise conv + silu (both directions) -------------
__global__ __launch_bounds__(256) void conv_silu_k(
    const float* __restrict__ xz,
    const float* __restrict__ wf, const float* __restrict__ bf,
    const float* __restrict__ wb, const float* __restrict__ bb,
    float* __restrict__ xf, float* __restrict__ xb)
{
  int idx = blockIdx.x * 256 + threadIdx.x;
  int dir = blockIdx.y;
  if (idx >= LSEQ * DINNER) return;
  int l = idx / DINNER, c = idx % DINNER;
  const float* w = (dir ? wb : wf) + c * KCONV;
  float acc = (dir ? bb : bf)[c];
#pragma unroll
  for (int k = 0; k < KCONV; k++) {
    int ls = l - (KCONV - 1) + k;
    if (ls >= 0) {
      int lsrc = dir ? (LSEQ - 1 - ls) : ls;
      acc += w[k] * xz[(size_t)lsrc * (2 * DINNER) + c];
    }
  }
  float sv = acc / (1.f + __expf(-acc));
  (dir ? xb : xf)[idx] = sv;
}

// ---------------- chunked selective scan (bf16 ycat out) ----------------
__global__ __launch_bounds__(256) void scan_k(
    const float* __restrict__ xc,
    const float* __restrict__ delta,
    const float* __restrict__ dbc,
    const float* __restrict__ A_log,
    const float* __restrict__ Dvec,
    u16* __restrict__ ycat,
    int col_off)
{
  __shared__ float sP[16 * 16 * 16];
  __shared__ float sQ[16 * 16 * 16];
  const int tid = threadIdx.x;
  const int c = tid >> 4;
  const int dl = tid & 15;
  const int d = blockIdx.x * 16 + dl;
  const int CH = LSEQ / 16;

  float Aa[DSTATE];
#pragma unroll
  for (int s = 0; s < DSTATE; s++) Aa[s] = -__expf(A_log[(size_t)d * DSTATE + s]);

  float aP[DSTATE], q[DSTATE];
#pragma unroll
  for (int s = 0; s < DSTATE; s++) { aP[s] = 1.f; q[s] = 0.f; }
  const int l0 = c * CH;
  for (int i = 0; i < CH; i++) {
    int l = l0 + i;
    float dt = delta[(size_t)l * DINNER + d];
    float dx = dt * xc[(size_t)l * DINNER + d];
    const float* bm = dbc + (size_t)l * DBC + DRANK;
#pragma unroll
    for (int s = 0; s < DSTATE; s++) {
      float a = __expf(dt * Aa[s]);
      q[s] = a * q[s] + dx * bm[s];
      aP[s] *= a;
    }
  }
#pragma unroll
  for (int s = 0; s < DSTATE; s++) {
    sP[(c * 16 + dl) * 16 + s] = aP[s];
    sQ[(c * 16 + dl) * 16 + s] = q[s];
  }
  __syncthreads();

  {
    const int d2 = tid >> 4, s2 = tid & 15;
    float h = 0.f;
    for (int cc = 0; cc < 16; cc++) {
      int idx = (cc * 16 + d2) * 16 + s2;
      float a = sP[idx], qq = sQ[idx];
      sP[idx] = h;
      h = a * h + qq;
    }
  }
  __syncthreads();

  float hs[DSTATE];
#pragma unroll
  for (int s = 0; s < DSTATE; s++) hs[s] = sP[(c * 16 + dl) * 16 + s];
  const float Dd = Dvec[d];
  for (int i = 0; i < CH; i++) {
    int l = l0 + i;
    float dt = delta[(size_t)l * DINNER + d];
    float xv = xc[(size_t)l * DINNER + d];
    float dx = dt * xv;
    const float* bm = dbc + (size_t)l * DBC + DRANK;
    const float* cm = bm + DSTATE;
    float y = 0.f;
#pragma unroll
    for (int s = 0; s < DSTATE; s++) {
      float a = __expf(dt * Aa[s]);
      hs[s] = a * hs[s] + dx * bm[s];
      y += hs[s] * cm[s];
    }
    ycat[(size_t)l * (2 * DINNER) + col_off + d] = f2bf(y + Dd * xv);
  }
}

// ---------------- row softmax (fp32 in, bf16 out) ----------------
__global__ __launch_bounds__(256) void softmax_k(const float* __restrict__ S,
                                                 u16* __restrict__ P) {
  int row = blockIdx.x, tid = threadIdx.x;
  __shared__ float buf[LSEQ];
  __shared__ float red[256];
  const float* r = S + (size_t)row * LSEQ;
  float m = -1e30f;
  for (int j = tid; j < LSEQ; j += 256) { float v = r[j]; buf[j] = v; m = fmaxf(m, v); }
  red[tid] = m; __syncthreads();
  for (int s = 128; s > 0; s >>= 1) { if (tid < s) red[tid] = fmaxf(red[tid], red[tid + s]); __syncthreads(); }
  m = red[0];
  __syncthreads();
  float sum = 0.f;
  for (int j = tid; j < LSEQ; j += 256) { float e = __expf(buf[j] - m); buf[j] = e; sum += e; }
  red[tid] = sum; __syncthreads();
  for (int s = 128; s > 0; s >>= 1) { if (tid < s) red[tid] += red[tid + s]; __syncthreads(); }
  float inv = 1.f / red[0];
  u16* pr = P + (size_t)row * LSEQ;
  for (int j = tid; j < LSEQ; j += 256) pr[j] = f2bf(buf[j] * inv);
}

// ---------------- g = y2 * silu(z) (bf16 out) ----------------
__global__ __launch_bounds__(256) void silumul_k(const float* __restrict__ y2,
                                                 const float* __restrict__ xz,
                                                 u16* __restrict__ g) {
  int idx = blockIdx.x * 256 + threadIdx.x;
  if (idx >= LSEQ * DINNER) return;
  int l = idx / DINNER, d = idx % DINNER;
  float z = xz[(size_t)l * (2 * DINNER) + DINNER + d];
  float s = z / (1.f + __expf(-z));
  g[idx] = f2bf(y2[idx] * s);
}

extern "C" void kernel_launch(void* const* d_in, const int* in_sizes, int n_in,
                              void* d_out, int out_size, void* d_ws, size_t ws_size,
                              hipStream_t stream) {
  const float* in_x      = (const float*)d_in[0];
  const float* norm_w    = (const float*)d_in[1];
  const float* in_proj_w = (const float*)d_in[2];
  const float* conv_f_w  = (const float*)d_in[3];
  const float* conv_f_b  = (const float*)d_in[4];
  const float* conv_b_w  = (const float*)d_in[5];
  const float* conv_b_b  = (const float*)d_in[6];
  const float* xproj_f_w = (const float*)d_in[7];
  const float* xproj_b_w = (const float*)d_in[8];
  const float* dt_f_w    = (const float*)d_in[9];
  const float* dt_f_b    = (const float*)d_in[10];
  const float* dt_b_w    = (const float*)d_in[11];
  const float* dt_b_b    = (const float*)d_in[12];
  const float* A_log_f   = (const float*)d_in[13];
  const float* D_f       = (const float*)d_in[14];
  const float* A_log_b   = (const float*)d_in[15];
  const float* D_b       = (const float*)d_in[16];
  const float* out_w     = (const float*)d_in[17];
  const float* token_wA  = (const float*)d_in[18];
  const float* token_wV  = (const float*)d_in[19];
  const float* pro_w     = (const float*)d_in[20];
  const float* pro_b     = (const float*)d_in[21];

  // ---- workspace carve (fp32 units) ----
  float* ws = (float*)d_ws;
  float* xbuf = ws; ws += LSEQ * DMODEL;            // 786432
  float* xz   = ws; ws += LSEQ * 2 * DINNER;        // 3145728
  float* xf   = ws; ws += LSEQ * DINNER;            // 1572864
  float* xb   = ws; ws += LSEQ * DINNER;            // 1572864
  float* dbcf = ws; ws += LSEQ * DBC;
  float* dbcb = ws; ws += LSEQ * DBC;
  float* delf = ws; ws += LSEQ * DINNER;            // alias: Smat fp32 (1M) after scan
  float* delb = ws; ws += LSEQ * DINNER;            // alias: Smat_bf after scan
  float* y2   = ws; ws += LSEQ * DINNER;
  u16* xn_bf   = (u16*)ws; ws += (LSEQ * DMODEL) / 2;
  u16* ycat_bf = (u16*)ws; ws += LSEQ * DINNER;     // [L][2*DINNER] u16
  u16* ypro_bf = (u16*)ws; ws += (LSEQ * DINNER) / 2;  // alias: g_bf after vv gemm
  u16* Wb      = (u16*)ws;                          // per-layer weight region (reused)
  u16* in_w_bf = Wb;                                // 3072*768
  u16* pw_bf   = in_w_bf + 3072 * 768;              // 1536*3072
  u16* wA_bf   = pw_bf + 1536 * 3072;               // 1024*1536
  u16* wVT_bf  = wA_bf + 1024 * 1536;               // 1536*1536
  u16* ow_bf   = wVT_bf + 1536 * 1536;              // 768*1536

  // aliases (verified live ranges)
  float* Smat    = delf;        // written after scans consume delf
  u16*   Smat_bf = (u16*)delb;
  u16*   vv_bf   = (u16*)xf;    // xf dead after scan-f
  u16*   vvT_bf  = (u16*)xb;    // xb dead after scan-b
  u16*   g_bf    = ypro_bf;     // ypro last read by vv gemm

  hipMemcpyAsync(xbuf, in_x, sizeof(float) * LSEQ * DMODEL,
                 hipMemcpyDeviceToDevice, stream);

  dim3 blk(256);
  for (int layer = 0; layer < NLAYER; layer++) {
    const float* nw  = norm_w    + (size_t)layer * DMODEL;
    const float* iw  = in_proj_w + (size_t)layer * 2 * DINNER * DMODEL;
    const float* cfw = conv_f_w  + (size_t)layer * DINNER * KCONV;
    const float* cfb = conv_f_b  + (size_t)layer * DINNER;
    const float* cbw = conv_b_w  + (size_t)layer * DINNER * KCONV;
    const float* cbb = conv_b_b  + (size_t)layer * DINNER;
    const float* xfw = xproj_f_w + (size_t)layer * DBC * DINNER;
    const float* xbw = xproj_b_w + (size_t)layer * DBC * DINNER;
    const float* dfw = dt_f_w    + (size_t)layer * DINNER * DRANK;
    const float* dfb = dt_f_b    + (size_t)layer * DINNER;
    const float* dbw = dt_b_w    + (size_t)layer * DINNER * DRANK;
    const float* dbb = dt_b_b    + (size_t)layer * DINNER;
    const float* Af  = A_log_f   + (size_t)layer * DINNER * DSTATE;
    const float* Df  = D_f       + (size_t)layer * DINNER;
    const float* Ab  = A_log_b   + (size_t)layer * DINNER * DSTATE;
    const float* Db  = D_b       + (size_t)layer * DINNER;
    const float* ow  = out_w     + (size_t)layer * DMODEL * DINNER;
    const float* wA  = token_wA  + (size_t)layer * LSEQ * DINNER;
    const float* wV  = token_wV  + (size_t)layer * DINNER * DINNER;
    const float* pw  = pro_w     + (size_t)layer * DINNER * 2 * DINNER;
    const float* pb  = pro_b     + (size_t)layer * DINNER;

    // weight conversions for this layer
    cvt_k<<<(3072 * 768 / 4 + 255) / 256, blk, 0, stream>>>(iw, in_w_bf, 3072 * 768 / 4);
    cvt_k<<<(1536 * 3072 / 4 + 255) / 256, blk, 0, stream>>>(pw, pw_bf, 1536 * 3072 / 4);
    cvt_k<<<(1024 * 1536 / 4 + 255) / 256, blk, 0, stream>>>(wA, wA_bf, 1024 * 1536 / 4);
    cvt_k<<<(768 * 1536 / 4 + 255) / 256, blk, 0, stream>>>(ow, ow_bf, 768 * 1536 / 4);
    transcvt_k<<<dim3(1536 / 32, 1536 / 32), blk, 0, stream>>>(wV, wVT_bf, 1536, 1536);

    rmsnorm_k<<<LSEQ, blk, 0, stream>>>(xbuf, nw, xn_bf);

    // xz = xn @ in_w^T   [1024,3072] k=768
    mgemm_k<0><<<dim3(3072 / 128, LSEQ / 128), blk, 0, stream>>>(
        xn_bf, DMODEL, in_w_bf, DMODEL, xz, 2 * DINNER, DMODEL, nullptr, nullptr, 0);

    conv_silu_k<<<dim3((LSEQ * DINNER) / 256, 2), blk, 0, stream>>>(
        xz, cfw, cfb, cbw, cbb, xf, xb);

    // dbc = x @ xproj^T  [1024,80] k=1536 (fp32)
    gemm_k<0><<<dim3(2, LSEQ / BM), blk, 0, stream>>>(
        xf, DINNER, xfw, DINNER, dbcf, DBC, LSEQ, DBC, DINNER, nullptr);
    gemm_k<0><<<dim3(2, LSEQ / BM), blk, 0, stream>>>(
        xb, DINNER, xbw, DINNER, dbcb, DBC, LSEQ, DBC, DINNER, nullptr);

    // delta = softplus(dlt @ dt_w^T + dt_b)  [1024,1536] k=48 (fp32)
    gemm_k<3><<<dim3(DINNER / BN, LSEQ / BM), blk, 0, stream>>>(
        dbcf, DBC, dfw, DRANK, delf, DINNER, LSEQ, DINNER, DRANK, dfb);
    gemm_k<3><<<dim3(DINNER / BN, LSEQ / BM), blk, 0, stream>>>(
        dbcb, DBC, dbw, DRANK, delb, DINNER, LSEQ, DINNER, DRANK, dbb);

    scan_k<<<DINNER / 16, blk, 0, stream>>>(xf, delf, dbcf, Af, Df, ycat_bf, 0);
    scan_k<<<DINNER / 16, blk, 0, stream>>>(xb, delb, dbcb, Ab, Db, ycat_bf, DINNER);

    // ypro = ycat @ pro_w^T + pro_b   [1024,1536] k=3072 -> bf16
    mgemm_k<9><<<dim3(DINNER / 128, LSEQ / 128), blk, 0, stream>>>(
        ycat_bf, 2 * DINNER, pw_bf, 2 * DINNER, ypro_bf, DINNER, 2 * DINNER,
        pb, nullptr, 0);

    // S = wA . ypro^T   [1024,1024] k=1536 -> fp32
    mgemm_k<0><<<dim3(LSEQ / 128, LSEQ / 128), blk, 0, stream>>>(
        wA_bf, DINNER, ypro_bf, DINNER, Smat, LSEQ, DINNER, nullptr, nullptr, 0);
    softmax_k<<<LSEQ, blk, 0, stream>>>(Smat, Smat_bf);

    // vv = ypro @ wV    [1024,1536] k=1536 -> bf16 (B = wV^T)
    mgemm_k<8><<<dim3(DINNER / 128, LSEQ / 128), blk, 0, stream>>>(
        ypro_bf, DINNER, wVT_bf, DINNER, vv_bf, DINNER, DINNER, nullptr, nullptr, 0);

    // vvT[e][l] = vv[l][e]
    transpose16_k<<<dim3(DINNER / 32, LSEQ / 32), blk, 0, stream>>>(
        vv_bf, vvT_bf, LSEQ, DINNER);

    // y2 = att @ vv     [1024,1536] k=1024 -> fp32 (B = vv^T)
    mgemm_k<0><<<dim3(DINNER / 128, LSEQ / 128), blk, 0, stream>>>(
        Smat_bf, LSEQ, vvT_bf, LSEQ, y2, DINNER, LSEQ, nullptr, nullptr, 0);

    silumul_k<<<(LSEQ * DINNER) / 256, blk, 0, stream>>>(y2, xz, g_bf);

    // x_next = x + g @ out_w^T   [1024,768] k=1536
    float* target = (layer == NLAYER - 1) ? (float*)d_out : xbuf;
    mgemm_k<4><<<dim3(DMODEL / 128, LSEQ / 128), blk, 0, stream>>>(
        g_bf, DINNER, ow_bf, DINNER, target, DMODEL, DINNER,
        nullptr, xbuf, DMODEL);
  }
}

// Round 5
// 710.189 us; speedup vs baseline: 2.7004x; 1.5609x over previous
//
#include <hip/hip_runtime.h>
#include <hip/hip_bf16.h>
#include <math.h>
#include <stdint.h>

#define LSEQ 1024
#define DMODEL 768
#define DINNER 1536
#define DSTATE 16
#define DRANK 48
#define KCONV 4
#define NLAYER 2
#define DBC 80  // DRANK + 2*DSTATE

typedef unsigned short u16;
typedef __attribute__((ext_vector_type(8))) __bf16 bf16x8;
typedef __attribute__((ext_vector_type(4))) float f32x4;
typedef __attribute__((ext_vector_type(4))) unsigned short us4;

__device__ __forceinline__ u16 f2bf(float f) {
  union { float f; unsigned u; } v; v.f = f;
  unsigned r = v.u + 0x7fffu + ((v.u >> 16) & 1u);  // RNE
  return (u16)(r >> 16);
}

// CK-style addrspace casts for global_load_lds (direct HBM->LDS DMA, 16B/lane)
__device__ __forceinline__ void gload16(const void* g, void* l) {
  auto gp = reinterpret_cast<const __attribute__((address_space(1))) uint32_t*>(
      reinterpret_cast<uintptr_t>(g));
  auto lp = reinterpret_cast<__attribute__((address_space(3))) uint32_t*>(
      reinterpret_cast<uintptr_t>(l));
  __builtin_amdgcn_global_load_lds(gp, lp, 16, 0, 0);
}

// ---------------- fp32 -> bf16 flat convert ----------------
__global__ __launch_bounds__(256) void cvt_k(const float* __restrict__ in,
                                             u16* __restrict__ out, int n4) {
  int i = blockIdx.x * 256 + threadIdx.x;
  if (i >= n4) return;
  float4 v = ((const float4*)in)[i];
  us4 o; o[0] = f2bf(v.x); o[1] = f2bf(v.y); o[2] = f2bf(v.z); o[3] = f2bf(v.w);
  ((us4*)out)[i] = o;
}

// ---------------- fp32 -> bf16 transpose-convert (out[c][r] = in[r][c]) -------
__global__ __launch_bounds__(256) void transcvt_k(const float* __restrict__ in,
                                                  u16* __restrict__ out,
                                                  int R, int C) {
  __shared__ float t[32][33];
  int c0 = blockIdx.x * 32, r0 = blockIdx.y * 32;
  int tx = threadIdx.x & 31, ty = threadIdx.x >> 5;
  for (int i = ty; i < 32; i += 8) t[i][tx] = in[(size_t)(r0 + i) * C + c0 + tx];
  __syncthreads();
  for (int i = ty; i < 32; i += 8)
    out[(size_t)(c0 + i) * R + r0 + tx] = f2bf(t[tx][i]);
}

// ---------------- bf16 -> bf16 transpose ----------------
__global__ __launch_bounds__(256) void transpose16_k(const u16* __restrict__ in,
                                                     u16* __restrict__ out,
                                                     int R, int C) {
  __shared__ u16 t[32][34];
  int c0 = blockIdx.x * 32, r0 = blockIdx.y * 32;
  int tx = threadIdx.x & 31, ty = threadIdx.x >> 5;
  for (int i = ty; i < 32; i += 8) t[i][tx] = in[(size_t)(r0 + i) * C + c0 + tx];
  __syncthreads();
  for (int i = ty; i < 32; i += 8)
    out[(size_t)(c0 + i) * R + r0 + tx] = t[tx][i];
}

// ---------------- rmsnorm (bf16 out) ----------------
__global__ __launch_bounds__(256) void rmsnorm_k(const float* __restrict__ x,
                                                 const float* __restrict__ w,
                                                 u16* __restrict__ xn) {
  int row = blockIdx.x;
  int tid = threadIdx.x;
  const float* xr = x + (size_t)row * DMODEL;
  float ss = 0.f;
  for (int j = tid; j < DMODEL; j += 256) { float v = xr[j]; ss += v * v; }
  __shared__ float red[256];
  red[tid] = ss; __syncthreads();
  for (int s = 128; s > 0; s >>= 1) { if (tid < s) red[tid] += red[tid + s]; __syncthreads(); }
  float scale = rsqrtf(red[0] / (float)DMODEL + 1e-5f);
  u16* outr = xn + (size_t)row * DMODEL;
  for (int j = tid; j < DMODEL; j += 256) outr[j] = f2bf(xr[j] * scale * w[j]);
}

// ---------------- MFMA bf16 GEMM, m97 structure ----------------
// C[m,n] = sum_k A[m,k]*B[n,k]; A [M,K] bf16, B [N,K] bf16 (NT).
// 128x128 tile, BK=32, 4 waves each 64x64 (4x4 frags of 16x16x32).
// EPI bit0: +bias[n]; bit2: +resid fp32; bit3: bf16 output.
template<int EPI>
__global__ __launch_bounds__(256) void mgemm_k(
    const u16* __restrict__ A, int lda,
    const u16* __restrict__ B, int ldb,
    void* __restrict__ Cv, int ldc, int K,
    const float* __restrict__ bias,
    const float* __restrict__ resid, int ldr)
{
  __shared__ u16 As[2][128 * 32];
  __shared__ u16 Bs[2][128 * 32];
  const int tid = threadIdx.x;
  const int lane = tid & 63;
  const int wid = tid >> 6;
  const int bm = blockIdx.y * 128;
  const int bn = blockIdx.x * 128;
  const int wm = (wid >> 1) * 64;
  const int wn = (wid & 1) * 64;

  const int r0 = wid * 16 + (lane >> 2);
  const int koff = (lane & 3) * 8;
  const u16* Ag0 = A + (size_t)(bm + r0) * lda + koff;
  const u16* Ag1 = Ag0 + (size_t)64 * lda;
  const u16* Bg0 = B + (size_t)(bn + r0) * ldb + koff;
  const u16* Bg1 = Bg0 + (size_t)64 * ldb;
  const int lb0 = wid * 512;
  const int lb1 = 2048 + wid * 512;

  f32x4 acc[4][4];
#pragma unroll
  for (int i = 0; i < 4; i++)
#pragma unroll
    for (int j = 0; j < 4; j++) acc[i][j] = (f32x4){0.f, 0.f, 0.f, 0.f};

#define STAGE(buf, k0) do { \
    gload16(Ag0 + (k0), &As[buf][lb0]); \
    gload16(Ag1 + (k0), &As[buf][lb1]); \
    gload16(Bg0 + (k0), &Bs[buf][lb0]); \
    gload16(Bg1 + (k0), &Bs[buf][lb1]); \
  } while (0)

  STAGE(0, 0);
  const int nk = K >> 5;
  const int fr = lane & 15;
  const int fks = (lane >> 4) * 8;

  for (int t = 0; t < nk; t++) {
    const int buf = t & 1;
    __syncthreads();
    if (t + 1 < nk) STAGE(buf ^ 1, (t + 1) << 5);
    bf16x8 af[4], bfv[4];
#pragma unroll
    for (int i = 0; i < 4; i++)
      af[i] = *reinterpret_cast<const bf16x8*>(&As[buf][(wm + i * 16 + fr) * 32 + fks]);
#pragma unroll
    for (int j = 0; j < 4; j++)
      bfv[j] = *reinterpret_cast<const bf16x8*>(&Bs[buf][(wn + j * 16 + fr) * 32 + fks]);
#pragma unroll
    for (int i = 0; i < 4; i++)
#pragma unroll
      for (int j = 0; j < 4; j++)
        acc[i][j] = __builtin_amdgcn_mfma_f32_16x16x32_bf16(af[i], bfv[j], acc[i][j], 0, 0, 0);
  }
#undef STAGE

  const int fq = lane >> 4;
#pragma unroll
  for (int i = 0; i < 4; i++) {
#pragma unroll
    for (int j = 0; j < 4; j++) {
      const int col = bn + wn + j * 16 + fr;
      const int row0 = bm + wm + i * 16 + fq * 4;
      float bv = (EPI & 1) ? bias[col] : 0.f;
#pragma unroll
      for (int r = 0; r < 4; r++) {
        float v = acc[i][j][r] + bv;
        if (EPI & 4) v += resid[(size_t)(row0 + r) * ldr + col];
        if (EPI & 8) ((u16*)Cv)[(size_t)(row0 + r) * ldc + col] = f2bf(v);
        else         ((float*)Cv)[(size_t)(row0 + r) * ldc + col] = v;
      }
    }
  }
}

// ---------------- thin dbc GEMM: partial[ks][1024][80], K-split 16x96 ---------
#define TG_R 16
#define TG_KC 96
#define TG_KS 16

__global__ __launch_bounds__(256) void thin_gemm_k(
    const float* __restrict__ A,   // [1024][1536]
    const float* __restrict__ B,   // [80][1536]
    float* __restrict__ partial)   // [TG_KS][1024][80]
{
  __shared__ float As[TG_R][100];  // stride 100: 16B-aligned, 4r+k banking
  __shared__ float Bs[80][100];
  const int tid = threadIdx.x;
  const int m0 = blockIdx.x * TG_R;
  const int ks = blockIdx.y;
  const int k0 = ks * TG_KC;

  for (int i = tid; i < 384; i += 256) {   // A tile: 16 rows x 96 = 384 float4 (BUGFIX: loop, not guard)
    int r = i / 24, q = i % 24;
    *(float4*)&As[r][q * 4] = *(const float4*)(A + (size_t)(m0 + r) * DINNER + k0 + q * 4);
  }
  for (int i = tid; i < 1920; i += 256) {  // B tile: 80 x 96 = 1920 float4
    int r = i / 24, q = i % 24;
    *(float4*)&Bs[r][q * 4] = *(const float4*)(B + (size_t)r * DINNER + k0 + q * 4);
  }
  __syncthreads();

  const int r = tid >> 4;         // 0..15
  const int c0 = (tid & 15) * 5;  // 0..75
  float acc[5] = {};
  for (int k = 0; k < TG_KC; k++) {
    float a = As[r][k];
#pragma unroll
    for (int j = 0; j < 5; j++) acc[j] += a * Bs[c0 + j][k];
  }
  float* out = partial + ((size_t)ks * LSEQ + m0 + r) * DBC + c0;
#pragma unroll
  for (int j = 0; j < 5; j++) out[j] = acc[j];
}

__global__ __launch_bounds__(256) void reduce_dbc_k(const float* __restrict__ partial,
                                                    float* __restrict__ out) {
  int i = blockIdx.x * 256 + threadIdx.x;  // LSEQ*DBC = 81920 total
  float s = 0.f;
#pragma unroll
  for (int ks = 0; ks < TG_KS; ks++) s += partial[(size_t)ks * (LSEQ * DBC) + i];
  out[i] = s;
}

// ---------------- fp32 tiled GEMM (delta: softplus path) ----------
#define BM 64
#define BN 64
#define BK 16

template<int EPI>  // bit0 bias, bit1 softplus
__global__ __launch_bounds__(256) void gemm_k(
    const float* __restrict__ A, int lda,
    const float* __restrict__ B, int ldb,
    float* __restrict__ C, int ldc,
    int M, int N, int K,
    const float* __restrict__ bias)
{
  __shared__ float Asf[BK][BM];
  __shared__ float Bsf[BK][BN + 4];
  const int tid = threadIdx.x;
  const int bm = blockIdx.y * BM;
  const int bn = blockIdx.x * BN;
  const int ar = tid >> 2;
  const int ak = (tid & 3) << 2;
  const int ty = tid >> 4, tx = tid & 15;
  float acc[4][4] = {};

  for (int k0 = 0; k0 < K; k0 += BK) {
    float4 av = *(const float4*)(A + (size_t)(bm + ar) * lda + k0 + ak);
    float4 bv = make_float4(0.f, 0.f, 0.f, 0.f);
    if (bn + ar < N) bv = *(const float4*)(B + (size_t)(bn + ar) * ldb + k0 + ak);
    __syncthreads();
    Asf[ak + 0][ar] = av.x; Asf[ak + 1][ar] = av.y;
    Asf[ak + 2][ar] = av.z; Asf[ak + 3][ar] = av.w;
    Bsf[ak + 0][ar] = bv.x; Bsf[ak + 1][ar] = bv.y;
    Bsf[ak + 2][ar] = bv.z; Bsf[ak + 3][ar] = bv.w;
    __syncthreads();
#pragma unroll
    for (int kk = 0; kk < BK; kk++) {
      float4 a4 = *(const float4*)&Asf[kk][ty * 4];
      float4 b4 = *(const float4*)&Bsf[kk][tx * 4];
      float a[4] = {a4.x, a4.y, a4.z, a4.w};
      float b[4] = {b4.x, b4.y, b4.z, b4.w};
#pragma unroll
      for (int i = 0; i < 4; i++)
#pragma unroll
        for (int j = 0; j < 4; j++)
          acc[i][j] += a[i] * b[j];
    }
  }

#pragma unroll
  for (int i = 0; i < 4; i++) {
    int row = bm + ty * 4 + i;
#pragma unroll
    for (int j = 0; j < 4; j++) {
      int col = bn + tx * 4 + j;
      if (col < N) {
        float v = acc[i][j];
        if (EPI & 1) v += bias[col];
        if (EPI & 2) v = (v > 20.f) ? v : log1pf(__expf(v));
        C[(size_t)row * ldc + col] = v;
      }
    }
  }
}

// ---------------- causal depthwise conv + silu (both directions) -------------
__global__ __launch_bounds__(256) void conv_silu_k(
    const float* __restrict__ xz,
    const float* __restrict__ wf, const float* __restrict__ bf,
    const float* __restrict__ wb, const float* __restrict__ bb,
    float* __restrict__ xf, float* __restrict__ xb)
{
  int idx = blockIdx.x * 256 + threadIdx.x;
  int dir = blockIdx.y;
  if (idx >= LSEQ * DINNER) return;
  int l = idx / DINNER, c = idx % DINNER;
  const float* w = (dir ? wb : wf) + c * KCONV;
  float acc = (dir ? bb : bf)[c];
#pragma unroll
  for (int k = 0; k < KCONV; k++) {
    int ls = l - (KCONV - 1) + k;
    if (ls >= 0) {
      int lsrc = dir ? (LSEQ - 1 - ls) : ls;
      acc += w[k] * xz[(size_t)lsrc * (2 * DINNER) + c];
    }
  }
  float sv = acc / (1.f + __expf(-acc));
  (dir ? xb : xf)[idx] = sv;
}

// ---------------- chunked selective scan: 64 chunks x 4 channels -------------
#define SCH 64   // chunks over L
#define SCPB 4   // channels per block
__global__ __launch_bounds__(256) void scan_k(
    const float* __restrict__ xc,
    const float* __restrict__ delta,
    const float* __restrict__ dbc,
    const float* __restrict__ A_log,
    const float* __restrict__ Dvec,
    u16* __restrict__ ycat,
    int col_off)
{
  __shared__ float sP[SCH * SCPB * DSTATE];  // 16 KB
  __shared__ float sQ[SCH * SCPB * DSTATE];
  const int tid = threadIdx.x;
  const int c = tid >> 2;       // chunk 0..63
  const int dl = tid & 3;       // channel-local
  const int d = blockIdx.x * SCPB + dl;
  const int CH = LSEQ / SCH;    // 16

  float Aa[DSTATE];
#pragma unroll
  for (int s = 0; s < DSTATE; s++) Aa[s] = -__expf(A_log[(size_t)d * DSTATE + s]);

  // phase 1: per-chunk affine summary
  float aP[DSTATE], q[DSTATE];
#pragma unroll
  for (int s = 0; s < DSTATE; s++) { aP[s] = 1.f; q[s] = 0.f; }
  const int l0 = c * CH;
  for (int i = 0; i < CH; i++) {
    int l = l0 + i;
    float dt = delta[(size_t)l * DINNER + d];
    float dx = dt * xc[(size_t)l * DINNER + d];
    const float* bm = dbc + (size_t)l * DBC + DRANK;
#pragma unroll
    for (int s = 0; s < DSTATE; s++) {
      float a = __expf(dt * Aa[s]);
      q[s] = a * q[s] + dx * bm[s];
      aP[s] *= a;
    }
  }
#pragma unroll
  for (int s = 0; s < DSTATE; s++) {
    sP[(c * SCPB + dl) * DSTATE + s] = aP[s];
    sQ[(c * SCPB + dl) * DSTATE + s] = q[s];
  }
  __syncthreads();

  // phase 2: serial combine across chunks (SCPB*16 = 64 threads active)
  if (tid < SCPB * DSTATE) {
    const int d2 = tid >> 4, s2 = tid & 15;
    float h = 0.f;
    for (int cc = 0; cc < SCH; cc++) {
      int idx = (cc * SCPB + d2) * DSTATE + s2;
      float a = sP[idx], qq = sQ[idx];
      sP[idx] = h;
      h = a * h + qq;
    }
  }
  __syncthreads();

  // phase 3: replay with carry-in, emit y
  float hs[DSTATE];
#pragma unroll
  for (int s = 0; s < DSTATE; s++) hs[s] = sP[(c * SCPB + dl) * DSTATE + s];
  const float Dd = Dvec[d];
  for (int i = 0; i < CH; i++) {
    int l = l0 + i;
    float dt = delta[(size_t)l * DINNER + d];
    float xv = xc[(size_t)l * DINNER + d];
    float dx = dt * xv;
    const float* bm = dbc + (size_t)l * DBC + DRANK;
    const float* cm = bm + DSTATE;
    float y = 0.f;
#pragma unroll
    for (int s = 0; s < DSTATE; s++) {
      float a = __expf(dt * Aa[s]);
      hs[s] = a * hs[s] + dx * bm[s];
      y += hs[s] * cm[s];
    }
    ycat[(size_t)l * (2 * DINNER) + col_off + d] = f2bf(y + Dd * xv);
  }
}

// ---------------- row softmax (fp32 in, bf16 out) ----------------
__global__ __launch_bounds__(256) void softmax_k(const float* __restrict__ S,
                                                 u16* __restrict__ P) {
  int row = blockIdx.x, tid = threadIdx.x;
  __shared__ float buf[LSEQ];
  __shared__ float red[256];
  const float* r = S + (size_t)row * LSEQ;
  float m = -1e30f;
  for (int j = tid; j < LSEQ; j += 256) { float v = r[j]; buf[j] = v; m = fmaxf(m, v); }
  red[tid] = m; __syncthreads();
  for (int s = 128; s > 0; s >>= 1) { if (tid < s) red[tid] = fmaxf(red[tid], red[tid + s]); __syncthreads(); }
  m = red[0];
  __syncthreads();
  float sum = 0.f;
  for (int j = tid; j < LSEQ; j += 256) { float e = __expf(buf[j] - m); buf[j] = e; sum += e; }
  red[tid] = sum; __syncthreads();
  for (int s = 128; s > 0; s >>= 1) { if (tid < s) red[tid] += red[tid + s]; __syncthreads(); }
  float inv = 1.f / red[0];
  u16* pr = P + (size_t)row * LSEQ;
  for (int j = tid; j < LSEQ; j += 256) pr[j] = f2bf(buf[j] * inv);
}

// ---------------- g = y2 * silu(z) (bf16 out) ----------------
__global__ __launch_bounds__(256) void silumul_k(const float* __restrict__ y2,
                                                 const float* __restrict__ xz,
                                                 u16* __restrict__ g) {
  int idx = blockIdx.x * 256 + threadIdx.x;
  if (idx >= LSEQ * DINNER) return;
  int l = idx / DINNER, d = idx % DINNER;
  float z = xz[(size_t)l * (2 * DINNER) + DINNER + d];
  float s = z / (1.f + __expf(-z));
  g[idx] = f2bf(y2[idx] * s);
}

extern "C" void kernel_launch(void* const* d_in, const int* in_sizes, int n_in,
                              void* d_out, int out_size, void* d_ws, size_t ws_size,
                              hipStream_t stream) {
  const float* in_x      = (const float*)d_in[0];
  const float* norm_w    = (const float*)d_in[1];
  const float* in_proj_w = (const float*)d_in[2];
  const float* conv_f_w  = (const float*)d_in[3];
  const float* conv_f_b  = (const float*)d_in[4];
  const float* conv_b_w  = (const float*)d_in[5];
  const float* conv_b_b  = (const float*)d_in[6];
  const float* xproj_f_w = (const float*)d_in[7];
  const float* xproj_b_w = (const float*)d_in[8];
  const float* dt_f_w    = (const float*)d_in[9];
  const float* dt_f_b    = (const float*)d_in[10];
  const float* dt_b_w    = (const float*)d_in[11];
  const float* dt_b_b    = (const float*)d_in[12];
  const float* A_log_f   = (const float*)d_in[13];
  const float* D_f       = (const float*)d_in[14];
  const float* A_log_b   = (const float*)d_in[15];
  const float* D_b       = (const float*)d_in[16];
  const float* out_w     = (const float*)d_in[17];
  const float* token_wA  = (const float*)d_in[18];
  const float* token_wV  = (const float*)d_in[19];
  const float* pro_w     = (const float*)d_in[20];
  const float* pro_b     = (const float*)d_in[21];

  // ---- workspace carve (fp32 units) ----
  float* ws = (float*)d_ws;
  float* xbuf = ws; ws += LSEQ * DMODEL;
  float* xz   = ws; ws += LSEQ * 2 * DINNER;
  float* xf   = ws; ws += LSEQ * DINNER;
  float* xb   = ws; ws += LSEQ * DINNER;
  float* dbcf = ws; ws += LSEQ * DBC;
  float* dbcb = ws; ws += LSEQ * DBC;
  float* delf = ws; ws += LSEQ * DINNER;   // alias: dbc partials pre-delta; Smat post-scan
  float* delb = ws; ws += LSEQ * DINNER;   // alias: Smat_bf post-scan
  float* y2   = ws; ws += LSEQ * DINNER;
  u16* xn_bf   = (u16*)ws; ws += (LSEQ * DMODEL) / 2;
  u16* ycat_bf = (u16*)ws; ws += LSEQ * DINNER;
  u16* ypro_bf = (u16*)ws; ws += (LSEQ * DINNER) / 2;
  u16* Wb      = (u16*)ws;
  u16* in_w_bf = Wb;
  u16* pw_bf   = in_w_bf + 3072 * 768;
  u16* wA_bf   = pw_bf + 1536 * 3072;
  u16* wVT_bf  = wA_bf + 1024 * 1536;
  u16* ow_bf   = wVT_bf + 1536 * 1536;

  // aliases (verified live ranges)
  float* dbc_part = delf;       // [16][1024][80] = 1.31M floats < 1.57M; dead before delta GEMM
  float* Smat    = delf;        // written after scans consume delf
  u16*   Smat_bf = (u16*)delb;
  u16*   vv_bf   = (u16*)xf;    // xf dead after scan-f
  u16*   vvT_bf  = (u16*)xb;    // xb dead after scan-b
  u16*   g_bf    = ypro_bf;     // ypro last read by vv gemm

  hipMemcpyAsync(xbuf, in_x, sizeof(float) * LSEQ * DMODEL,
                 hipMemcpyDeviceToDevice, stream);

  dim3 blk(256);
  for (int layer = 0; layer < NLAYER; layer++) {
    const float* nw  = norm_w    + (size_t)layer * DMODEL;
    const float* iw  = in_proj_w + (size_t)layer * 2 * DINNER * DMODEL;
    const float* cfw = conv_f_w  + (size_t)layer * DINNER * KCONV;
    const float* cfb = conv_f_b  + (size_t)layer * DINNER;
    const float* cbw = conv_b_w  + (size_t)layer * DINNER * KCONV;
    const float* cbb = conv_b_b  + (size_t)layer * DINNER;
    const float* xfw = xproj_f_w + (size_t)layer * DBC * DINNER;
    const float* xbw = xproj_b_w + (size_t)layer * DBC * DINNER;
    const float* dfw = dt_f_w    + (size_t)layer * DINNER * DRANK;
    const float* dfb = dt_f_b    + (size_t)layer * DINNER;
    const float* dbw = dt_b_w    + (size_t)layer * DINNER * DRANK;
    const float* dbb = dt_b_b    + (size_t)layer * DINNER;
    const float* Af  = A_log_f   + (size_t)layer * DINNER * DSTATE;
    const float* Df  = D_f       + (size_t)layer * DINNER;
    const float* Ab  = A_log_b   + (size_t)layer * DINNER * DSTATE;
    const float* Db  = D_b       + (size_t)layer * DINNER;
    const float* ow  = out_w     + (size_t)layer * DMODEL * DINNER;
    const float* wA  = token_wA  + (size_t)layer * LSEQ * DINNER;
    const float* wV  = token_wV  + (size_t)layer * DINNER * DINNER;
    const float* pw  = pro_w     + (size_t)layer * DINNER * 2 * DINNER;
    const float* pb  = pro_b     + (size_t)layer * DINNER;

    // weight conversions for this layer
    cvt_k<<<(3072 * 768 / 4 + 255) / 256, blk, 0, stream>>>(iw, in_w_bf, 3072 * 768 / 4);
    cvt_k<<<(1536 * 3072 / 4 + 255) / 256, blk, 0, stream>>>(pw, pw_bf, 1536 * 3072 / 4);
    cvt_k<<<(1024 * 1536 / 4 + 255) / 256, blk, 0, stream>>>(wA, wA_bf, 1024 * 1536 / 4);
    cvt_k<<<(768 * 1536 / 4 + 255) / 256, blk, 0, stream>>>(ow, ow_bf, 768 * 1536 / 4);
    transcvt_k<<<dim3(1536 / 32, 1536 / 32), blk, 0, stream>>>(wV, wVT_bf, 1536, 1536);

    rmsnorm_k<<<LSEQ, blk, 0, stream>>>(xbuf, nw, xn_bf);

    // xz = xn @ in_w^T   [1024,3072] k=768
    mgemm_k<0><<<dim3(3072 / 128, LSEQ / 128), blk, 0, stream>>>(
        xn_bf, DMODEL, in_w_bf, DMODEL, xz, 2 * DINNER, DMODEL, nullptr, nullptr, 0);

    conv_silu_k<<<dim3((LSEQ * DINNER) / 256, 2), blk, 0, stream>>>(
        xz, cfw, cfb, cbw, cbb, xf, xb);

    // dbc = x @ xproj^T  [1024,80] k=1536 (fp32, K-split thin GEMM)
    thin_gemm_k<<<dim3(LSEQ / TG_R, TG_KS), blk, 0, stream>>>(xf, xfw, dbc_part);
    reduce_dbc_k<<<(LSEQ * DBC) / 256, blk, 0, stream>>>(dbc_part, dbcf);
    thin_gemm_k<<<dim3(LSEQ / TG_R, TG_KS), blk, 0, stream>>>(xb, xbw, dbc_part);
    reduce_dbc_k<<<(LSEQ * DBC) / 256, blk, 0, stream>>>(dbc_part, dbcb);

    // delta = softplus(dlt @ dt_w^T + dt_b)  [1024,1536] k=48 (fp32)
    gemm_k<3><<<dim3(DINNER / BN, LSEQ / BM), blk, 0, stream>>>(
        dbcf, DBC, dfw, DRANK, delf, DINNER, LSEQ, DINNER, DRANK, dfb);
    gemm_k<3><<<dim3(DINNER / BN, LSEQ / BM), blk, 0, stream>>>(
        dbcb, DBC, dbw, DRANK, delb, DINNER, LSEQ, DINNER, DRANK, dbb);

    scan_k<<<DINNER / SCPB, blk, 0, stream>>>(xf, delf, dbcf, Af, Df, ycat_bf, 0);
    scan_k<<<DINNER / SCPB, blk, 0, stream>>>(xb, delb, dbcb, Ab, Db, ycat_bf, DINNER);

    // ypro = ycat @ pro_w^T + pro_b   [1024,1536] k=3072 -> bf16
    mgemm_k<9><<<dim3(DINNER / 128, LSEQ / 128), blk, 0, stream>>>(
        ycat_bf, 2 * DINNER, pw_bf, 2 * DINNER, ypro_bf, DINNER, 2 * DINNER,
        pb, nullptr, 0);

    // S = wA . ypro^T   [1024,1024] k=1536 -> fp32
    mgemm_k<0><<<dim3(LSEQ / 128, LSEQ / 128), blk, 0, stream>>>(
        wA_bf, DINNER, ypro_bf, DINNER, Smat, LSEQ, DINNER, nullptr, nullptr, 0);
    softmax_k<<<LSEQ, blk, 0, stream>>>(Smat, Smat_bf);

    // vv = ypro @ wV    [1024,1536] k=1536 -> bf16 (B = wV^T)
    mgemm_k<8><<<dim3(DINNER / 128, LSEQ / 128), blk, 0, stream>>>(
        ypro_bf, DINNER, wVT_bf, DINNER, vv_bf, DINNER, DINNER, nullptr, nullptr, 0);

    // vvT[e][l] = vv[l][e]
    transpose16_k<<<dim3(DINNER / 32, LSEQ / 32), blk, 0, stream>>>(
        vv_bf, vvT_bf, LSEQ, DINNER);

    // y2 = att @ vv     [1024,1536] k=1024 -> fp32 (B = vv^T)
    mgemm_k<0><<<dim3(DINNER / 128, LSEQ / 128), blk, 0, stream>>>(
        Smat_bf, LSEQ, vvT_bf, LSEQ, y2, DINNER, LSEQ, nullptr, nullptr, 0);

    silumul_k<<<(LSEQ * DINNER) / 256, blk, 0, stream>>>(y2, xz, g_bf);

    // x_next = x + g @ out_w^T   [1024,768] k=1536
    float* target = (layer == NLAYER - 1) ? (float*)d_out : xbuf;
    mgemm_k<4><<<dim3(DMODEL / 128, LSEQ / 128), blk, 0, stream>>>(
        g_bf, DINNER, ow_bf, DINNER, target, DMODEL, DINNER,
        nullptr, xbuf, DMODEL);
  }
}